// Round 8
// baseline (381.352 us; speedup 1.0000x reference)
//
#include <hip/hip_runtime.h>

// LocalGraphTransformerEncoder on MI355X (gfx950). Round 14.
// R13: 289us, 17 dispatches, all kernels <42us (top-5 = harness fills).
// R14 structural merges:
//  - epi+Wo fused into ONE K=1280 GEMM via precomputed W2o[h]=evW2_h@Wo_h
//    (k_prep, 74 blocks, once): out = [t0|t1|t2|t3|vs] @ [W2o;Wo] + bias2 + x.
//    Removes oi bf16 round-trip + 1 dispatch/layer.
//  - kNN folded into k_csr (thread-per-node top-3 from smem coords, same
//    packed-key order incl sqrt). Removes k_knn dispatch + knn buffer.
// Dispatches 17 -> 15.
// Standing lessons: no persistent grid barriers (R8/R9 ~65us each, fence/L2
// flush-bound); sim+exp must be edge-parallel (R11); accum serial edge chain
// per block must be <=32 (R12).

#define MAXE  16384
#define NONX  22080
#define BF16_TOTAL 1441792

typedef __attribute__((ext_vector_type(8))) short bf16x8;
typedef __attribute__((ext_vector_type(4))) float f32x4;

struct PtrPack { const void* p[23]; };

__device__ __forceinline__ float bf2f(unsigned short s) {
  return __uint_as_float(((unsigned)s) << 16);
}
__device__ __forceinline__ unsigned short f2bf(float f) {
  unsigned u = __float_as_uint(f);
  u += 0x7fffu + ((u >> 16) & 1u);
  return (unsigned short)(u >> 16);
}
__device__ __forceinline__ float gelu_f(float x) {
  return 0.5f * x * (1.0f + erff(x * 0.70710678118654752440f));
}
__device__ __forceinline__ float wave_red_sum(float v) {
#pragma unroll
  for (int o = 32; o > 0; o >>= 1) v += __shfl_xor(v, o);
  return v;
}

__device__ __forceinline__ void edge_feats(int i, int j, float cxi, float cyi,
                                           float cxj, float cyj, float lsd, float* e) {
  float dx = cxj - cxi, dy = cyj - cyi;
  float dist = sqrtf(dx * dx + dy * dy + 1e-8f);
  e[0] = dx; e[1] = dy; e[2] = dist; e[3] = dist / lsd;
  bool qic = (i == 0), kic = (j == 0), eye = (i == j);
  e[4] = qic ? 1.f : 0.f;
  e[5] = kic ? 1.f : 0.f;
  e[6] = eye ? 1.f : 0.f;
  e[7] = (!qic && !kic && !eye) ? 1.f : 0.f;
  int hi = (i == 0) ? 0 : ((i < 128) ? 1 : 2);
  int hj = (j == 0) ? 0 : ((j < 128) ? 1 : 2);
  e[8] = (hi == hj) ? 1.f : 0.f;
  int hd = hj - hi;
  e[9] = (float)(hd < 0 ? -hd : hd);
}

// ---------- convert: fp32 smalls + bf16 weights + valid + rowsum zero ----------
__global__ __launch_bounds__(256) void k_convert(PtrPack pp, float* __restrict__ blobF,
                                                 unsigned short* __restrict__ blobB,
                                                 int* __restrict__ valid,
                                                 float* __restrict__ rowsum,
                                                 int* __restrict__ gctr) {
  bool isf32 = (*(const unsigned*)pp.p[15] == 0x3F800000u);
  int t = threadIdx.x;
  if (blockIdx.x == 0 && t == 0) *gctr = 0;
  if (blockIdx.x < 1024) {
    if (blockIdx.x < 32) rowsum[blockIdx.x * 256 + t] = 0.f;
    int r = blockIdx.x;
    int idx = r * 256 + t;
    float v = isf32 ? ((const float*)pp.p[0])[idx]
                    : bf2f(((const unsigned short*)pp.p[0])[idx]);
    blobF[idx] = v;
    __shared__ float s[4];
    float a = wave_red_sum(fabsf(v));
    if ((t & 63) == 0) s[t >> 6] = a;
    __syncthreads();
    if (t == 0) valid[r] = ((s[0] + s[1] + s[2] + s[3]) > 0.0f) || ((r & 255) == 0);
  } else {
    const int fst[16] = {0,2048,7680,8192,10240,10304,15936,16448,16960,17472,17984,18496,19008,19520,21568,22080};
    const int fsz[15] = {2048,5632,512,2048,8,5632,512,512,512,512,512,512,512,2048,512};
    const int fin[15] = {1,5,6,7,8,9,10,12,14,15,16,17,18,20,22};
    const int bst[8]  = {0,131072,262144,393216,524288,655360,1179648,1441792};
    const int bin[7]  = {2,3,4,13,11,19,21};
    const int NUNITS = NONX + BF16_TOTAL / 4;   // bf16 handled 4-at-a-time
    for (int u = (blockIdx.x - 1024) * 256 + t; u < NUNITS; u += 1024 * 256) {
      if (u < NONX) {
        int s = 0;
        while (s < 14 && u >= fst[s + 1]) ++s;
        int e = u - fst[s];
        float v = 0.f;
        if (e < fsz[s]) v = isf32 ? ((const float*)pp.p[fin[s]])[e]
                                  : bf2f(((const unsigned short*)pp.p[fin[s]])[e]);
        blobF[262144 + u] = v;
      } else {
        int bi = (u - NONX) * 4;       // quad of bf16 elems; sections 64-aligned
        int s = 0;
        while (s < 6 && bi >= bst[s + 1]) ++s;
        int e = bi - bst[s];
        ushort4 o;
        if (isf32) {
          const float* sp = (const float*)pp.p[bin[s]] + e;
          o.x = f2bf(sp[0]); o.y = f2bf(sp[1]); o.z = f2bf(sp[2]); o.w = f2bf(sp[3]);
        } else {
          o = *(const ushort4*)((const unsigned short*)pp.p[bin[s]] + e);
        }
        *(ushort4*)&blobB[bi] = o;
      }
    }
  }
}

// ---------- prep: Bcat=[W2o(4x256);Wo] bf16 + bias2 = evB2@Wo + bo ----------
// grid 74: x<64 -> (l,h,ug): W2o rows; x in {64,65} -> bias2[l]; x in 66..73
// -> copy Wo rows into Bcat rows 1024..1279.
__global__ __launch_bounds__(256) void k_prep(const unsigned short* __restrict__ evW2B,
                                              const unsigned short* __restrict__ WoB,
                                              const float* __restrict__ evB2,
                                              const float* __restrict__ boB,
                                              unsigned short* __restrict__ Bcat,
                                              float* __restrict__ bias2) {
  int x = blockIdx.x, n = threadIdx.x;
  if (x < 64) {
    int l = x >> 5, rem = x & 31;
    int h = rem >> 3, ug = rem & 7;
    const unsigned short* W2 = evW2B + l * 65536;
    const unsigned short* Wo = WoB + l * 65536;
    __shared__ short sWo[16384];           // Wo rows h*64..h*64+63 (bf16)
    for (int k = n; k < 16384; k += 256) sWo[k] = (short)Wo[h * 64 * 256 + k];
    __syncthreads();
    int u0 = ug * 32;
    for (int u = u0; u < u0 + 32; ++u) {
      const unsigned short* wrow = W2 + u * 256 + h * 64;
      float acc = 0.f;
#pragma unroll 8
      for (int dh = 0; dh < 64; ++dh)
        acc += bf2f(wrow[dh]) * bf2f((unsigned short)sWo[dh * 256 + n]);
      Bcat[(size_t)l * 327680 + (size_t)(h * 256 + u) * 256 + n] = f2bf(acc);
    }
  } else if (x < 66) {
    int l = x - 64;
    const unsigned short* Wo = WoB + l * 65536;
    float acc = boB[l * 256 + n];
    for (int c = 0; c < 256; ++c)
      acc += evB2[l * 256 + c] * bf2f(Wo[c * 256 + n]);
    bias2[l * 256 + n] = acc;
  } else {
    int idx = x - 66;
    int l = idx >> 2, q = idx & 3;
    const unsigned short* Wo = WoB + l * 65536;
    for (int rr = 0; rr < 64; ++rr) {
      int c = q * 64 + rr;
      Bcat[(size_t)l * 327680 + (size_t)(1024 + c) * 256 + n] = Wo[c * 256 + n];
    }
  }
}

// ---------- CSR build with integrated kNN ----------
__global__ __launch_bounds__(256) void k_csr(const float* __restrict__ cf,
                                             const int* __restrict__ valid,
                                             float* __restrict__ lsbuf,
                                             int* __restrict__ deg, int* __restrict__ rowptr,
                                             int* __restrict__ rowof, int* __restrict__ colsb,
                                             int* __restrict__ gctr) {
  int b = blockIdx.x, t = threadIdx.x;
  __shared__ unsigned adjw[256][8];
  __shared__ float2 scc[256];
  __shared__ int sval[256];
  __shared__ float sred[8];
  __shared__ int wsum[4];
  __shared__ int sbase;

  int r = b * 256 + t;
  const float2* cc = (const float2*)cf + b * 256;
  float2 ci = cc[t];
  int lv = valid[r];
  scc[t] = ci;
  sval[t] = lv;
#pragma unroll
  for (int w = 0; w < 8; ++w) adjw[t][w] = 0u;
  __syncthreads();

  // kNN: thread t = node, serial top-3 over 255 candidates (packed keys,
  // sqrt kept to match reference tie behavior)
  unsigned long long k0 = ~0ull, k1 = ~0ull, k2 = ~0ull;
  if (t != 0 && lv) {
    for (int j = 1; j < 256; ++j) {
      if (j == t || !sval[j]) continue;
      float dx = ci.x - scc[j].x, dy = ci.y - scc[j].y;
      float dd = sqrtf(dx * dx + dy * dy);
      unsigned long long kk = (((unsigned long long)__float_as_uint(dd)) << 32) | (unsigned)j;
      if (kk < k2) {
        if (kk < k1) {
          k2 = k1;
          if (kk < k0) { k1 = k0; k0 = kk; } else k1 = kk;
        } else k2 = kk;
      }
    }
  }

  atomicOr(&adjw[t][t >> 5], 1u << (t & 31));
  if (t >= 1 && lv) {
    atomicOr(&adjw[0][t >> 5], 1u << (t & 31));
    atomicOr(&adjw[t][0], 1u);
  }
  unsigned long long ks[3] = {k0, k1, k2};
#pragma unroll
  for (int s = 0; s < 3; ++s) {
    if (ks[s] != ~0ull) {
      int j = (int)(ks[s] & 0xFFFFFFFFull);
      atomicOr(&adjw[t][j >> 5], 1u << (j & 31));
      atomicOr(&adjw[j][t >> 5], 1u << (t & 31));
    }
  }
  float cdist = sqrtf(ci.x * ci.x + ci.y * ci.y + 1e-8f);
  int nvm = (t >= 1) && lv;
  float rs = wave_red_sum(nvm ? cdist : 0.0f);
  float rc = wave_red_sum(nvm ? 1.0f : 0.0f);
  if ((t & 63) == 0) { sred[t >> 6] = rs; sred[4 + (t >> 6)] = rc; }
  __syncthreads();

  if (t == 0) {
    float totd = sred[0] + sred[1] + sred[2] + sred[3];
    float totc = sred[4] + sred[5] + sred[6] + sred[7];
    float ls = totd / fmaxf(totc, 1.0f);
    ls = (ls > 0.0f) ? ls : 1.0f;
    lsbuf[b] = fmaxf(ls, 1e-6f);
  }

  int dg = 0;
#pragma unroll
  for (int w = 0; w < 8; ++w) dg += __popc(adjw[t][w]);

  int lane = t & 63, wv = t >> 6;
  int x = dg;
#pragma unroll
  for (int off = 1; off < 64; off <<= 1) {
    int y = __shfl_up(x, off);
    if (lane >= off) x += y;
  }
  if (lane == 63) wsum[wv] = x;
  __syncthreads();
  if (t == 0) sbase = atomicAdd(gctr, wsum[0] + wsum[1] + wsum[2] + wsum[3]);
  __syncthreads();
  int woff = 0;
#pragma unroll
  for (int k2i = 0; k2i < 4; ++k2i) woff += (k2i < wv) ? wsum[k2i] : 0;
  int off0 = sbase + woff + x - dg;

  rowptr[r] = off0;
  deg[r] = dg;
  int o = off0;
#pragma unroll
  for (int w = 0; w < 8; ++w) {
    unsigned bits = adjw[t][w];
    while (bits) {
      int bp = __ffs(bits) - 1;
      colsb[o] = w * 32 + bp;
      rowof[o] = r;
      ++o;
      bits &= bits - 1;
    }
  }
}

// ---------- bf16 MFMA GEMM body: 16x64 tile, BK=64, full-K reg prefetch ----
// AMODE: 0=bf16 A | 1=gated fp32 (gate +512, lda=1024) | 2=plain fp32 | 3=LN-fused fp32
// OMODE: 0=fp32 | 1=probe bf16/fp32 | 2=bf16
// K must be a multiple of 256. AMODE 3 requires K==256.
template <int AMODE, int OMODE>
__device__ __forceinline__ void mfma_body(const void* Aptr, int lda,
                                          const unsigned short* __restrict__ B, int ldb, int n0B,
                                          const float* __restrict__ bias,
                                          const float* resid,
                                          void* C, int ldc, int n0C,
                                          int m0, int K, bool obf,
                                          const float* __restrict__ lnG,
                                          const float* __restrict__ lnB) {
  __shared__ short As[16][72];
  __shared__ short Bs[64][72];
  __shared__ float sG[256], sB2[256];
  int t = threadIdx.x, lane = t & 63, w = t >> 6;

  int am = t >> 3, ak = (t & 7) * 8;   // A staging (t < 128): 16 rows x 64 k
  int bk = t >> 2, bn = (t & 3) * 16;  // B staging (all): 64 k x 64 n

  f32x4 acc;
  acc[0] = 0.f; acc[1] = 0.f; acc[2] = 0.f; acc[3] = 0.f;

  for (int kc = 0; kc < K; kc += 256) {
    // ---- prefetch 4 rounds of A and B into registers (independent loads) ----
    bf16x8 aB[4];
    float4 aF[4][2];
    float4 gF[4][2];
    bf16x8 bR[4][2];
#pragma unroll
    for (int r = 0; r < 4; ++r) {
      int k0 = kc + r * 64;
      if (t < 128) {
        if (AMODE == 0) {
          aB[r] = *(const bf16x8*)((const unsigned short*)Aptr +
                                   (size_t)(m0 + am) * lda + k0 + ak);
        } else {
          const float* ap = (const float*)Aptr + (size_t)(m0 + am) * lda + k0 + ak;
          aF[r][0] = *(const float4*)ap;
          aF[r][1] = *(const float4*)(ap + 4);
          if (AMODE == 1) {
            gF[r][0] = *(const float4*)(ap + 512);
            gF[r][1] = *(const float4*)(ap + 516);
          }
        }
      }
      const unsigned short* bp = B + (size_t)(k0 + bk) * ldb + n0B + bn;
      bR[r][0] = *(const bf16x8*)bp;
      bR[r][1] = *(const bf16x8*)(bp + 8);
    }

    // ---- AMODE 3: LN gamma/beta to LDS; row stats from prefetched regs ----
    float mm = 0.f, rstd = 0.f;
    if (AMODE == 3) {
      sG[t] = lnG[t]; sB2[t] = lnB[t];
      if (t < 128) {
        float s = 0.f, ss = 0.f;
#pragma unroll
        for (int r = 0; r < 4; ++r)
#pragma unroll
          for (int h2 = 0; h2 < 2; ++h2) {
            float4 v4 = aF[r][h2];
            s += v4.x + v4.y + v4.z + v4.w;
            ss += v4.x * v4.x + v4.y * v4.y + v4.z * v4.z + v4.w * v4.w;
          }
        s += __shfl_xor(s, 1); s += __shfl_xor(s, 2); s += __shfl_xor(s, 4);
        ss += __shfl_xor(ss, 1); ss += __shfl_xor(ss, 2); ss += __shfl_xor(ss, 4);
        mm = s * (1.f / 256.f);
        float var = ss * (1.f / 256.f) - mm * mm;
        rstd = 1.f / sqrtf(var + 1e-5f);
      }
      __syncthreads();
    }

    // ---- 4 rounds: stage from registers, MFMA ----
#pragma unroll
    for (int r = 0; r < 4; ++r) {
      if (t < 128) {
        if (AMODE == 0) {
          *(bf16x8*)&As[am][ak] = aB[r];
        } else if (AMODE == 1) {
          float4 a0 = aF[r][0], a1 = aF[r][1];
          float4 g0 = gF[r][0], g1 = gF[r][1];
          short tmp[8];
          tmp[0] = (short)f2bf(a0.x * gelu_f(g0.x));
          tmp[1] = (short)f2bf(a0.y * gelu_f(g0.y));
          tmp[2] = (short)f2bf(a0.z * gelu_f(g0.z));
          tmp[3] = (short)f2bf(a0.w * gelu_f(g0.w));
          tmp[4] = (short)f2bf(a1.x * gelu_f(g1.x));
          tmp[5] = (short)f2bf(a1.y * gelu_f(g1.y));
          tmp[6] = (short)f2bf(a1.z * gelu_f(g1.z));
          tmp[7] = (short)f2bf(a1.w * gelu_f(g1.w));
          *(bf16x8*)&As[am][ak] = *(bf16x8*)tmp;
        } else if (AMODE == 2) {
          float4 a0 = aF[r][0], a1 = aF[r][1];
          short tmp[8];
          tmp[0] = (short)f2bf(a0.x); tmp[1] = (short)f2bf(a0.y);
          tmp[2] = (short)f2bf(a0.z); tmp[3] = (short)f2bf(a0.w);
          tmp[4] = (short)f2bf(a1.x); tmp[5] = (short)f2bf(a1.y);
          tmp[6] = (short)f2bf(a1.z); tmp[7] = (short)f2bf(a1.w);
          *(bf16x8*)&As[am][ak] = *(bf16x8*)tmp;
        } else {
          float4 a0 = aF[r][0], a1 = aF[r][1];
          int kb = kc + r * 64 + ak;
          short tmp[8];
          tmp[0] = (short)f2bf((a0.x - mm) * rstd * sG[kb + 0] + sB2[kb + 0]);
          tmp[1] = (short)f2bf((a0.y - mm) * rstd * sG[kb + 1] + sB2[kb + 1]);
          tmp[2] = (short)f2bf((a0.z - mm) * rstd * sG[kb + 2] + sB2[kb + 2]);
          tmp[3] = (short)f2bf((a0.w - mm) * rstd * sG[kb + 3] + sB2[kb + 3]);
          tmp[4] = (short)f2bf((a1.x - mm) * rstd * sG[kb + 4] + sB2[kb + 4]);
          tmp[5] = (short)f2bf((a1.y - mm) * rstd * sG[kb + 5] + sB2[kb + 5]);
          tmp[6] = (short)f2bf((a1.z - mm) * rstd * sG[kb + 6] + sB2[kb + 6]);
          tmp[7] = (short)f2bf((a1.w - mm) * rstd * sG[kb + 7] + sB2[kb + 7]);
          *(bf16x8*)&As[am][ak] = *(bf16x8*)tmp;
        }
      }
      {
        bf16x8 bv0 = bR[r][0], bv1 = bR[r][1];
#pragma unroll
        for (int i2 = 0; i2 < 8; ++i2) Bs[bn + i2][bk] = bv0[i2];
#pragma unroll
        for (int i2 = 0; i2 < 8; ++i2) Bs[bn + 8 + i2][bk] = bv1[i2];
      }
      __syncthreads();
      int q = lane >> 4;
      bf16x8 af0 = *(const bf16x8*)&As[lane & 15][q * 8];
      bf16x8 af1 = *(const bf16x8*)&As[lane & 15][32 + q * 8];
      bf16x8 bf0 = *(const bf16x8*)&Bs[w * 16 + (lane & 15)][q * 8];
      bf16x8 bf1 = *(const bf16x8*)&Bs[w * 16 + (lane & 15)][32 + q * 8];
      acc = __builtin_amdgcn_mfma_f32_16x16x32_bf16(af0, bf0, acc, 0, 0, 0);
      acc = __builtin_amdgcn_mfma_f32_16x16x32_bf16(af1, bf1, acc, 0, 0, 0);
      __syncthreads();
    }
  }

  int q = lane >> 4;
  int cn = w * 16 + (lane & 15);
  int col = n0C + cn;
  float bv = bias ? bias[n0B + cn] : 0.0f;
#pragma unroll
  for (int rr = 0; rr < 4; ++rr) {
    int row = m0 + q * 4 + rr;
    float v = acc[rr] + bv;
    if (resid) v += resid[(size_t)row * ldc + col];
    if (OMODE == 2 || (OMODE == 1 && obf)) {
      ((unsigned short*)C)[(size_t)row * ldc + col] = f2bf(v);
    } else {
      ((float*)C)[(size_t)row * ldc + col] = v;
    }
  }
}

template <int AMODE, int OMODE>
__global__ __launch_bounds__(256) void k_mfma(const void* A, int lda, int aYoffBytes,
                                              const unsigned short* B, int ldb,
                                              const float* bias, const float* resid,
                                              void* C, int ldc, int K,
                                              const unsigned* probe,
                                              const float* lnG, const float* lnB) {
  bool obf = (OMODE == 1) && probe && (*probe != 0x3F800000u);
  int n0 = blockIdx.y * 64;
  const void* Ap = (const char*)A + (size_t)aYoffBytes * blockIdx.y;
  mfma_body<AMODE, OMODE>(Ap, lda, B, ldb, n0, bias, resid, C, ldc, n0,
                          blockIdx.x * 16, K, obf, lnG, lnB);
}

// QKV with fused LN: Wq/Wk/Wv sections are 131072 elems apart in the bf16 blob.
__global__ __launch_bounds__(256) void k_mfma_qkv(const float* X,
                                                  const float* lnG, const float* lnB,
                                                  const unsigned short* WqL, float* qkv) {
  int sel = blockIdx.y >> 2;
  const unsigned short* B = WqL + sel * 131072;
  int n0B = (blockIdx.y & 3) * 64;
  int n0C = blockIdx.y * 64;
  mfma_body<3, 0>(X, 256, B, 256, n0B, nullptr, nullptr, qkv, 768, n0C,
                  blockIdx.x * 16, 256, false, lnG, lnB);
}

// ---------- simz: sim + exp + rowsum atomics (edge-parallel) ----------
// Blocks 0..3 additionally zero the hub rows' tbx slots (r = bx*256).
__global__ __launch_bounds__(256) void k_simz(const float* __restrict__ cf,
                                              const float* __restrict__ qkv,
                                              const int* __restrict__ rowof,
                                              const int* __restrict__ colsb,
                                              const int* __restrict__ gctr,
                                              const float* __restrict__ lsbuf,
                                              const float* __restrict__ ebW1,
                                              const float* __restrict__ ebB1,
                                              const float* __restrict__ ebW2,
                                              const float* __restrict__ ebB2,
                                              float* __restrict__ esim,
                                              float* __restrict__ rowsum,
                                              float* __restrict__ tbx) {
  int t = threadIdx.x;
  if (blockIdx.x < 4) {
    int hr = blockIdx.x * 256;
    size_t tz = (size_t)hr * 1280 + t;
    tbx[tz] = 0.f; tbx[tz + 256] = 0.f; tbx[tz + 512] = 0.f;
    tbx[tz + 768] = 0.f; tbx[tz + 1024] = 0.f;
  }
  int E = *gctr;
  int lane = t & 63, w = t >> 6;
  float W1r[4][10], B1r[4], W2r[4][4];
#pragma unroll
  for (int kk = 0; kk < 4; ++kk) {
    int c = kk * 64 + lane;
    B1r[kk] = ebB1[c];
#pragma unroll
    for (int f = 0; f < 10; ++f) W1r[kk][f] = ebW1[f * 256 + c];
    float4 w2 = *(const float4*)(ebW2 + c * 4);
    W2r[kk][0] = w2.x; W2r[kk][1] = w2.y; W2r[kk][2] = w2.z; W2r[kk][3] = w2.w;
  }
  float b20 = ebB2[0], b21 = ebB2[1], b22 = ebB2[2], b23 = ebB2[3];
  for (int g = blockIdx.x * 4 + w; g < E; g += 4096) {
    int r = rowof[g], j = colsb[g];
    int b = r >> 8, i = r & 255;
    float ls = lsbuf[b];
    const float2* cc = (const float2*)cf;
    float2 ci = cc[b * 256 + i], cj = cc[b * 256 + j];
    float ef[10];
    edge_feats(i, j, ci.x, ci.y, cj.x, cj.y, ls, ef);
    float red[8];
#pragma unroll
    for (int z = 0; z < 8; ++z) red[z] = 0.0f;
#pragma unroll
    for (int kk = 0; kk < 4; ++kk) {
      int c = kk * 64 + lane;
      float h1 = B1r[kk];
#pragma unroll
      for (int f = 0; f < 10; ++f) h1 += ef[f] * W1r[kk][f];
      float g1 = gelu_f(h1);
      red[4] += g1 * W2r[kk][0];
      red[5] += g1 * W2r[kk][1];
      red[6] += g1 * W2r[kk][2];
      red[7] += g1 * W2r[kk][3];
      red[kk] = qkv[(size_t)r * 768 + c] * qkv[((size_t)(b * 256 + j)) * 768 + 256 + c];
    }
#pragma unroll
    for (int z = 0; z < 8; ++z) {
#pragma unroll
      for (int o = 32; o > 0; o >>= 1) red[z] += __shfl_xor(red[z], o);
    }
    if (lane == 0) {
      float e0 = expf(red[0] * 0.125f + red[4] + b20);
      float e1 = expf(red[1] * 0.125f + red[5] + b21);
      float e2 = expf(red[2] * 0.125f + red[6] + b22);
      float e3 = expf(red[3] * 0.125f + red[7] + b23);
      *(float4*)&esim[(size_t)g * 4] = make_float4(e0, e1, e2, e3);
      atomicAdd(&rowsum[r * 4 + 0], e0);
      atomicAdd(&rowsum[r * 4 + 1], e1);
      atomicAdd(&rowsum[r * 4 + 2], e2);
      atomicAdd(&rowsum[r * 4 + 3], e3);
    }
  }
}

// ---------- accum: hybrid chunked (32-edge chunks) -> tbx [t0|t1|t2|t3|vs] ----
// grid = 1052: x<1024 -> (row x, chunk 0); x>=1024 -> hub rows' chunks 1..7.
__global__ __launch_bounds__(256, 8) void k_accum(const float* __restrict__ cf,
                                                  const float* __restrict__ qkv,
                                                  const int* __restrict__ rowptr,
                                                  const int* __restrict__ deg,
                                                  const int* __restrict__ colsb,
                                                  const float* __restrict__ esim,
                                                  const float* __restrict__ rowsum,
                                                  const float* __restrict__ lsbuf,
                                                  const float* __restrict__ evW1,
                                                  const float* __restrict__ evB1,
                                                  float* __restrict__ tbx) {
  int x = blockIdx.x;
  int r, ch;
  if (x < 1024) { r = x; ch = 0; }
  else { int i5 = x - 1024; r = (i5 / 7) * 256; ch = 1 + i5 % 7; }
  int d = deg[r];
  int e0 = ch * 32;
  if (e0 >= d) return;
  int n = min(32, d - e0);
  bool whole = (ch == 0) && (d <= 32);
  int base = rowptr[r] + e0;
  int b = r >> 8, i = r & 255;
  int u = threadIdx.x, h = u >> 6;

  __shared__ int scols[32];
  __shared__ float4 sattn[32];
  __shared__ float sef[32][10];
  if (u < n) {
    float4 S4 = *(const float4*)&rowsum[r * 4];
    int j = colsb[base + u];
    scols[u] = j;
    float4 e = *(const float4*)&esim[(size_t)(base + u) * 4];
    sattn[u] = make_float4(e.x / S4.x, e.y / S4.y, e.z / S4.z, e.w / S4.w);
    float ls = lsbuf[b];
    const float2* cc = (const float2*)cf;
    float2 ci = cc[b * 256 + i], cj = cc[b * 256 + j];
    float ef[10];
    edge_feats(i, j, ci.x, ci.y, cj.x, cj.y, ls, ef);
#pragma unroll
    for (int f = 0; f < 10; ++f) sef[u][f] = ef[f];
  }
  __syncthreads();

  float evb = evB1[u];
  float w1r[10];
#pragma unroll
  for (int f = 0; f < 10; ++f) w1r[f] = evW1[f * 256 + u];
  float t0 = 0.f, t1 = 0.f, t2 = 0.f, t3 = 0.f, va = 0.f;
#pragma unroll 4
  for (int e = 0; e < n; ++e) {
    float4 a = sattn[e];
    int j = scols[e];
    float h1 = evb;
#pragma unroll
    for (int f = 0; f < 10; ++f) h1 += sef[e][f] * w1r[f];
    float g1 = gelu_f(h1);
    t0 += a.x * g1; t1 += a.y * g1; t2 += a.z * g1; t3 += a.w * g1;
    float ah = (h == 0) ? a.x : (h == 1) ? a.y : (h == 2) ? a.z : a.w;
    va += ah * qkv[((size_t)(b * 256 + j)) * 768 + 512 + u];
  }
  size_t tbase = (size_t)r * 1280 + u;
  if (whole) {
    tbx[tbase]        = t0;
    tbx[tbase + 256]  = t1;
    tbx[tbase + 512]  = t2;
    tbx[tbase + 768]  = t3;
    tbx[tbase + 1024] = va;
  } else {
    atomicAdd(&tbx[tbase], t0);
    atomicAdd(&tbx[tbase + 256], t1);
    atomicAdd(&tbx[tbase + 512], t2);
    atomicAdd(&tbx[tbase + 768], t3);
    atomicAdd(&tbx[tbase + 1024], va);
  }
}

extern "C" void kernel_launch(void* const* d_in, const int* in_sizes, int n_in,
                              void* d_out, int out_size, void* d_ws, size_t ws_size,
                              hipStream_t stream) {
  (void)in_sizes; (void)n_in; (void)out_size; (void)ws_size;

  char* wp = (char*)d_ws;
  auto carve = [&](size_t bytes) -> char* {
    char* p = wp;
    wp += ((bytes + 255) / 256) * 256;
    return p;
  };
  int*   gctr   = (int*)carve(4);
  float* lsb    = (float*)carve(16);
  int*   valid  = (int*)carve(1024 * 4);
  int*   deg    = (int*)carve(1024 * 4);
  int*   rowptr = (int*)carve(1024 * 4);
  int*   rowof  = (int*)carve(MAXE * 4);
  int*   colsb  = (int*)carve(MAXE * 4);
  float* rowsum = (float*)carve(8192 * 4);
  float* sim    = (float*)carve((size_t)MAXE * 16);
  float* blobF  = (float*)carve((size_t)(262144 + NONX) * 4);
  unsigned short* blobB = (unsigned short*)carve((size_t)BF16_TOTAL * 2);
  unsigned short* Bcat  = (unsigned short*)carve((size_t)2 * 327680 * 2);
  float* bias2  = (float*)carve(512 * 4);
  float* qkv    = (float*)carve((size_t)1024 * 768 * 4);
  float* xcur   = (float*)carve((size_t)262144 * 4);
  float* tbx    = (float*)carve((size_t)1024 * 1280 * 4);  // [t0|t1|t2|t3|vs]
  float* tb     = (float*)carve((size_t)1048576 * 4);      // FF hidden

  // fp32 blob pointers
  const float* Xf    = blobF + 0;
  const float* Cf    = blobF + 262144;
  const float* ebW1  = blobF + 264192;
  const float* ebB1  = blobF + 269824;
  const float* ebW2  = blobF + 270336;
  const float* ebB2  = blobF + 272384;
  const float* evW1  = blobF + 272448;
  const float* evB1  = blobF + 278080;
  const float* evB2  = blobF + 278592;
  const float* boB   = blobF + 279104;
  const float* ln1w  = blobF + 279616;
  const float* ln1b  = blobF + 280128;
  const float* ln2w  = blobF + 280640;
  const float* ln2b  = blobF + 281152;
  const float* ffb1  = blobF + 281664;
  const float* ffb2  = blobF + 283712;
  // bf16 blob pointers
  const unsigned short* WqB   = blobB + 0;
  const unsigned short* WoB   = blobB + 393216;
  const unsigned short* evW2B = blobB + 524288;
  const unsigned short* ffw1B = blobB + 655360;
  const unsigned short* ffw2B = blobB + 1179648;

  PtrPack pp;
  for (int i = 0; i < 23; ++i) pp.p[i] = d_in[i];
  const unsigned* probe = (const unsigned*)d_in[15];

  k_convert<<<2048, 256, 0, stream>>>(pp, blobF, blobB, valid, rowsum, gctr);
  k_prep<<<74, 256, 0, stream>>>(evW2B, WoB, evB2, boB, Bcat, bias2);
  k_csr<<<4, 256, 0, stream>>>(Cf, valid, lsb, deg, rowptr, rowof, colsb, gctr);

  for (int l = 0; l < 2; ++l) {
    const float* xsrc = (l == 0) ? Xf : xcur;
    float* rsumL = rowsum + l * 4096;
    k_mfma_qkv<<<dim3(64, 12), 256, 0, stream>>>(xsrc, ln1w + l * 256, ln1b + l * 256,
                                                 WqB + l * 65536, qkv);
    k_simz<<<1024, 256, 0, stream>>>(Cf, qkv, rowof, colsb, gctr, lsb,
                                     ebW1 + l * 2816, ebB1 + l * 256,
                                     ebW2 + l * 1024, ebB2 + l * 4,
                                     sim, rsumL, tbx);
    k_accum<<<1052, 256, 0, stream>>>(Cf, qkv, rowptr, deg, colsb, sim, rsumL, lsb,
                                      evW1 + l * 2816, evB1 + l * 256, tbx);
    // fused epi+Wo GEMM: xcur = [t0|t1|t2|t3|vs] @ [W2o;Wo] + bias2 + xsrc
    k_mfma<2, 0><<<dim3(64, 4), 256, 0, stream>>>(tbx, 1280, 0, Bcat + l * 327680, 256,
                                                  bias2 + l * 256, xsrc, xcur, 256, 1280,
                                                  nullptr, nullptr, nullptr);
    // FF1 with fused LN2
    k_mfma<3, 0><<<dim3(64, 16), 256, 0, stream>>>(xcur, 256, 0, ffw1B + l * 262144, 1024,
                                                   ffb1 + l * 1024, nullptr, tb, 1024, 256,
                                                   nullptr, ln2w + l * 256, ln2b + l * 256);
    // FF2 gated + residual
    if (l == 0) {
      k_mfma<1, 0><<<dim3(64, 4), 256, 0, stream>>>(tb, 1024, 0, ffw2B + l * 131072, 256,
                                                    ffb2 + l * 256, xcur, xcur, 256, 512,
                                                    nullptr, nullptr, nullptr);
    } else {
      k_mfma<1, 1><<<dim3(64, 4), 256, 0, stream>>>(tb, 1024, 0, ffw2B + l * 131072, 256,
                                                    ffb2 + l * 256, xcur, d_out, 256, 512,
                                                    probe, nullptr, nullptr);
    }
  }
}

// Round 9
// 333.014 us; speedup vs baseline: 1.1452x; 1.1452x over previous
//
#include <hip/hip_runtime.h>

// LocalGraphTransformerEncoder on MI355X (gfx950). Round 15.
// R14: 381us -- epi+Wo K=1280 fusion GOOD; kNN-folded-into-csr BAD
// (k_csr 68.5us @ 0.15% occupancy: serial 255-iter per-thread scan replaced
// the wave-parallel k_knn. Lesson: never shrink a phase's parallel width to
// save a dispatch). R15: restore wave-parallel k_knn, fused with k_prep in
// ONE dispatch (blocks 0..255 = kNN, 256..329 = prep; both depend only on
// k_convert). Keep epi+Wo fusion. Dispatches 15.
// Standing lessons: no persistent grid barriers (R8/R9 ~65us each);
// sim+exp edge-parallel (R11); accum chunk <=32 edges/block (R12).

#define MAXE  16384
#define NONX  22080
#define BF16_TOTAL 1441792

typedef __attribute__((ext_vector_type(8))) short bf16x8;
typedef __attribute__((ext_vector_type(4))) float f32x4;

struct PtrPack { const void* p[23]; };

__device__ __forceinline__ float bf2f(unsigned short s) {
  return __uint_as_float(((unsigned)s) << 16);
}
__device__ __forceinline__ unsigned short f2bf(float f) {
  unsigned u = __float_as_uint(f);
  u += 0x7fffu + ((u >> 16) & 1u);
  return (unsigned short)(u >> 16);
}
__device__ __forceinline__ float gelu_f(float x) {
  return 0.5f * x * (1.0f + erff(x * 0.70710678118654752440f));
}
__device__ __forceinline__ float wave_red_sum(float v) {
#pragma unroll
  for (int o = 32; o > 0; o >>= 1) v += __shfl_xor(v, o);
  return v;
}

__device__ __forceinline__ void edge_feats(int i, int j, float cxi, float cyi,
                                           float cxj, float cyj, float lsd, float* e) {
  float dx = cxj - cxi, dy = cyj - cyi;
  float dist = sqrtf(dx * dx + dy * dy + 1e-8f);
  e[0] = dx; e[1] = dy; e[2] = dist; e[3] = dist / lsd;
  bool qic = (i == 0), kic = (j == 0), eye = (i == j);
  e[4] = qic ? 1.f : 0.f;
  e[5] = kic ? 1.f : 0.f;
  e[6] = eye ? 1.f : 0.f;
  e[7] = (!qic && !kic && !eye) ? 1.f : 0.f;
  int hi = (i == 0) ? 0 : ((i < 128) ? 1 : 2);
  int hj = (j == 0) ? 0 : ((j < 128) ? 1 : 2);
  e[8] = (hi == hj) ? 1.f : 0.f;
  int hd = hj - hi;
  e[9] = (float)(hd < 0 ? -hd : hd);
}

// ---------- convert: fp32 smalls + bf16 weights + valid + rowsum zero ----------
__global__ __launch_bounds__(256) void k_convert(PtrPack pp, float* __restrict__ blobF,
                                                 unsigned short* __restrict__ blobB,
                                                 int* __restrict__ valid,
                                                 float* __restrict__ rowsum,
                                                 int* __restrict__ gctr) {
  bool isf32 = (*(const unsigned*)pp.p[15] == 0x3F800000u);
  int t = threadIdx.x;
  if (blockIdx.x == 0 && t == 0) *gctr = 0;
  if (blockIdx.x < 1024) {
    if (blockIdx.x < 32) rowsum[blockIdx.x * 256 + t] = 0.f;
    int r = blockIdx.x;
    int idx = r * 256 + t;
    float v = isf32 ? ((const float*)pp.p[0])[idx]
                    : bf2f(((const unsigned short*)pp.p[0])[idx]);
    blobF[idx] = v;
    __shared__ float s[4];
    float a = wave_red_sum(fabsf(v));
    if ((t & 63) == 0) s[t >> 6] = a;
    __syncthreads();
    if (t == 0) valid[r] = ((s[0] + s[1] + s[2] + s[3]) > 0.0f) || ((r & 255) == 0);
  } else {
    const int fst[16] = {0,2048,7680,8192,10240,10304,15936,16448,16960,17472,17984,18496,19008,19520,21568,22080};
    const int fsz[15] = {2048,5632,512,2048,8,5632,512,512,512,512,512,512,512,2048,512};
    const int fin[15] = {1,5,6,7,8,9,10,12,14,15,16,17,18,20,22};
    const int bst[8]  = {0,131072,262144,393216,524288,655360,1179648,1441792};
    const int bin[7]  = {2,3,4,13,11,19,21};
    const int NUNITS = NONX + BF16_TOTAL / 4;   // bf16 handled 4-at-a-time
    for (int u = (blockIdx.x - 1024) * 256 + t; u < NUNITS; u += 1024 * 256) {
      if (u < NONX) {
        int s = 0;
        while (s < 14 && u >= fst[s + 1]) ++s;
        int e = u - fst[s];
        float v = 0.f;
        if (e < fsz[s]) v = isf32 ? ((const float*)pp.p[fin[s]])[e]
                                  : bf2f(((const unsigned short*)pp.p[fin[s]])[e]);
        blobF[262144 + u] = v;
      } else {
        int bi = (u - NONX) * 4;       // quad of bf16 elems; sections 64-aligned
        int s = 0;
        while (s < 6 && bi >= bst[s + 1]) ++s;
        int e = bi - bst[s];
        ushort4 o;
        if (isf32) {
          const float* sp = (const float*)pp.p[bin[s]] + e;
          o.x = f2bf(sp[0]); o.y = f2bf(sp[1]); o.z = f2bf(sp[2]); o.w = f2bf(sp[3]);
        } else {
          o = *(const ushort4*)((const unsigned short*)pp.p[bin[s]] + e);
        }
        *(ushort4*)&blobB[bi] = o;
      }
    }
  }
}

// ---------- kNN (wave-parallel) + prep (Bcat/bias2) in one dispatch ----------
// blocks 0..255: kNN, one wave per node, 3-round packed-key argmin.
// blocks 256..319: W2o rows; 320,321: bias2; 322..329: Wo copy.
__global__ __launch_bounds__(256) void k_knn_prep(const float* __restrict__ cf,
                                                  const int* __restrict__ valid,
                                                  int* __restrict__ knn,
                                                  const unsigned short* __restrict__ evW2B,
                                                  const unsigned short* __restrict__ WoB,
                                                  const float* __restrict__ evB2,
                                                  const float* __restrict__ boB,
                                                  unsigned short* __restrict__ Bcat,
                                                  float* __restrict__ bias2) {
  int blk = blockIdx.x;
  if (blk < 256) {
    int b = blk >> 6;
    int w = threadIdx.x >> 6, lane = threadIdx.x & 63;
    int i = (blk & 63) * 4 + w;
    const float2* cc = (const float2*)(cf + b * 512);
    float2 ci = cc[i];
    bool vi = (valid[b * 256 + i] != 0) && (i != 0);
    unsigned long long key[4];
#pragma unroll
    for (int k = 0; k < 4; ++k) {
      int j = lane + 64 * k;
      bool ok = vi && (j != 0) && (j != i) && (valid[b * 256 + j] != 0);
      unsigned long long kk = ~0ull;
      if (ok) {
        float2 cj = cc[j];
        float dx = ci.x - cj.x, dy = ci.y - cj.y;
        float dd = sqrtf(dx * dx + dy * dy);
        kk = (((unsigned long long)__float_as_uint(dd)) << 32) | (unsigned)j;
      }
      key[k] = kk;
    }
    int out[3];
#pragma unroll
    for (int rnd = 0; rnd < 3; ++rnd) {
      unsigned long long m = key[0];
      if (key[1] < m) m = key[1];
      if (key[2] < m) m = key[2];
      if (key[3] < m) m = key[3];
#pragma unroll
      for (int o = 32; o > 0; o >>= 1) {
        unsigned long long om = __shfl_xor(m, o);
        if (om < m) m = om;
      }
      out[rnd] = (m != ~0ull) ? (int)(m & 0xFFFFFFFFull) : -1;
#pragma unroll
      for (int k = 0; k < 4; ++k)
        if (key[k] == m) key[k] = ~0ull;
    }
    if (lane == 0) {
      knn[(b * 256 + i) * 3 + 0] = out[0];
      knn[(b * 256 + i) * 3 + 1] = out[1];
      knn[(b * 256 + i) * 3 + 2] = out[2];
    }
  } else {
    int x = blk - 256, n = threadIdx.x;
    if (x < 64) {
      int l = x >> 5, rem = x & 31;
      int h = rem >> 3, ug = rem & 7;
      const unsigned short* W2 = evW2B + l * 65536;
      const unsigned short* Wo = WoB + l * 65536;
      __shared__ short sWo[16384];         // Wo rows h*64..h*64+63 (bf16)
      for (int k = n; k < 16384; k += 256) sWo[k] = (short)Wo[h * 64 * 256 + k];
      __syncthreads();
      int u0 = ug * 32;
      for (int u = u0; u < u0 + 32; ++u) {
        const unsigned short* wrow = W2 + u * 256 + h * 64;
        float acc = 0.f;
#pragma unroll 8
        for (int dh = 0; dh < 64; ++dh)
          acc += bf2f(wrow[dh]) * bf2f((unsigned short)sWo[dh * 256 + n]);
        Bcat[(size_t)l * 327680 + (size_t)(h * 256 + u) * 256 + n] = f2bf(acc);
      }
    } else if (x < 66) {
      int l = x - 64;
      const unsigned short* Wo = WoB + l * 65536;
      float acc = boB[l * 256 + n];
      for (int c = 0; c < 256; ++c)
        acc += evB2[l * 256 + c] * bf2f(Wo[c * 256 + n]);
      bias2[l * 256 + n] = acc;
    } else {
      int idx = x - 66;
      int l = idx >> 2, q = idx & 3;
      const unsigned short* Wo = WoB + l * 65536;
      for (int rr = 0; rr < 64; ++rr) {
        int c = q * 64 + rr;
        Bcat[(size_t)l * 327680 + (size_t)(1024 + c) * 256 + n] = Wo[c * 256 + n];
      }
    }
  }
}

// ---------- CSR build (shuffle scan) ----------
__global__ __launch_bounds__(256) void k_csr(const float* __restrict__ cf,
                                             const int* __restrict__ valid,
                                             const int* __restrict__ knn,
                                             float* __restrict__ lsbuf,
                                             int* __restrict__ deg, int* __restrict__ rowptr,
                                             int* __restrict__ rowof, int* __restrict__ colsb,
                                             int* __restrict__ gctr) {
  int b = blockIdx.x, t = threadIdx.x;
  __shared__ unsigned adjw[256][8];
  __shared__ float sred[8];
  __shared__ int wsum[4];
  __shared__ int sbase;

  int r = b * 256 + t;
  float cx = cf[r * 2 + 0], cy = cf[r * 2 + 1];
  int lv = valid[r];
#pragma unroll
  for (int w = 0; w < 8; ++w) adjw[t][w] = 0u;
  __syncthreads();

  atomicOr(&adjw[t][t >> 5], 1u << (t & 31));
  if (t >= 1 && lv) {
    atomicOr(&adjw[0][t >> 5], 1u << (t & 31));
    atomicOr(&adjw[t][0], 1u);
  }
#pragma unroll
  for (int s = 0; s < 3; ++s) {
    int j = knn[r * 3 + s];
    if (j >= 0) {
      atomicOr(&adjw[t][j >> 5], 1u << (j & 31));
      atomicOr(&adjw[j][t >> 5], 1u << (t & 31));
    }
  }
  float cdist = sqrtf(cx * cx + cy * cy + 1e-8f);
  int nvm = (t >= 1) && lv;
  float rs = wave_red_sum(nvm ? cdist : 0.0f);
  float rc = wave_red_sum(nvm ? 1.0f : 0.0f);
  if ((t & 63) == 0) { sred[t >> 6] = rs; sred[4 + (t >> 6)] = rc; }
  __syncthreads();

  if (t == 0) {
    float totd = sred[0] + sred[1] + sred[2] + sred[3];
    float totc = sred[4] + sred[5] + sred[6] + sred[7];
    float ls = totd / fmaxf(totc, 1.0f);
    ls = (ls > 0.0f) ? ls : 1.0f;
    lsbuf[b] = fmaxf(ls, 1e-6f);
  }

  int dg = 0;
#pragma unroll
  for (int w = 0; w < 8; ++w) dg += __popc(adjw[t][w]);

  int lane = t & 63, wv = t >> 6;
  int x = dg;
#pragma unroll
  for (int off = 1; off < 64; off <<= 1) {
    int y = __shfl_up(x, off);
    if (lane >= off) x += y;
  }
  if (lane == 63) wsum[wv] = x;
  __syncthreads();
  if (t == 0) sbase = atomicAdd(gctr, wsum[0] + wsum[1] + wsum[2] + wsum[3]);
  __syncthreads();
  int woff = 0;
#pragma unroll
  for (int k2i = 0; k2i < 4; ++k2i) woff += (k2i < wv) ? wsum[k2i] : 0;
  int off0 = sbase + woff + x - dg;

  rowptr[r] = off0;
  deg[r] = dg;
  int o = off0;
#pragma unroll
  for (int w = 0; w < 8; ++w) {
    unsigned bits = adjw[t][w];
    while (bits) {
      int bp = __ffs(bits) - 1;
      colsb[o] = w * 32 + bp;
      rowof[o] = r;
      ++o;
      bits &= bits - 1;
    }
  }
}

// ---------- bf16 MFMA GEMM body: 16x64 tile, BK=64, full-K reg prefetch ----
// AMODE: 0=bf16 A | 1=gated fp32 (gate +512, lda=1024) | 2=plain fp32 | 3=LN-fused fp32
// OMODE: 0=fp32 | 1=probe bf16/fp32 | 2=bf16
// K must be a multiple of 256. AMODE 3 requires K==256.
template <int AMODE, int OMODE>
__device__ __forceinline__ void mfma_body(const void* Aptr, int lda,
                                          const unsigned short* __restrict__ B, int ldb, int n0B,
                                          const float* __restrict__ bias,
                                          const float* resid,
                                          void* C, int ldc, int n0C,
                                          int m0, int K, bool obf,
                                          const float* __restrict__ lnG,
                                          const float* __restrict__ lnB) {
  __shared__ short As[16][72];
  __shared__ short Bs[64][72];
  __shared__ float sG[256], sB2[256];
  int t = threadIdx.x, lane = t & 63, w = t >> 6;

  int am = t >> 3, ak = (t & 7) * 8;   // A staging (t < 128): 16 rows x 64 k
  int bk = t >> 2, bn = (t & 3) * 16;  // B staging (all): 64 k x 64 n

  f32x4 acc;
  acc[0] = 0.f; acc[1] = 0.f; acc[2] = 0.f; acc[3] = 0.f;

  for (int kc = 0; kc < K; kc += 256) {
    // ---- prefetch 4 rounds of A and B into registers (independent loads) ----
    bf16x8 aB[4];
    float4 aF[4][2];
    float4 gF[4][2];
    bf16x8 bR[4][2];
#pragma unroll
    for (int r = 0; r < 4; ++r) {
      int k0 = kc + r * 64;
      if (t < 128) {
        if (AMODE == 0) {
          aB[r] = *(const bf16x8*)((const unsigned short*)Aptr +
                                   (size_t)(m0 + am) * lda + k0 + ak);
        } else {
          const float* ap = (const float*)Aptr + (size_t)(m0 + am) * lda + k0 + ak;
          aF[r][0] = *(const float4*)ap;
          aF[r][1] = *(const float4*)(ap + 4);
          if (AMODE == 1) {
            gF[r][0] = *(const float4*)(ap + 512);
            gF[r][1] = *(const float4*)(ap + 516);
          }
        }
      }
      const unsigned short* bp = B + (size_t)(k0 + bk) * ldb + n0B + bn;
      bR[r][0] = *(const bf16x8*)bp;
      bR[r][1] = *(const bf16x8*)(bp + 8);
    }

    // ---- AMODE 3: LN gamma/beta to LDS; row stats from prefetched regs ----
    float mm = 0.f, rstd = 0.f;
    if (AMODE == 3) {
      sG[t] = lnG[t]; sB2[t] = lnB[t];
      if (t < 128) {
        float s = 0.f, ss = 0.f;
#pragma unroll
        for (int r = 0; r < 4; ++r)
#pragma unroll
          for (int h2 = 0; h2 < 2; ++h2) {
            float4 v4 = aF[r][h2];
            s += v4.x + v4.y + v4.z + v4.w;
            ss += v4.x * v4.x + v4.y * v4.y + v4.z * v4.z + v4.w * v4.w;
          }
        s += __shfl_xor(s, 1); s += __shfl_xor(s, 2); s += __shfl_xor(s, 4);
        ss += __shfl_xor(ss, 1); ss += __shfl_xor(ss, 2); ss += __shfl_xor(ss, 4);
        mm = s * (1.f / 256.f);
        float var = ss * (1.f / 256.f) - mm * mm;
        rstd = 1.f / sqrtf(var + 1e-5f);
      }
      __syncthreads();
    }

    // ---- 4 rounds: stage from registers, MFMA ----
#pragma unroll
    for (int r = 0; r < 4; ++r) {
      if (t < 128) {
        if (AMODE == 0) {
          *(bf16x8*)&As[am][ak] = aB[r];
        } else if (AMODE == 1) {
          float4 a0 = aF[r][0], a1 = aF[r][1];
          float4 g0 = gF[r][0], g1 = gF[r][1];
          short tmp[8];
          tmp[0] = (short)f2bf(a0.x * gelu_f(g0.x));
          tmp[1] = (short)f2bf(a0.y * gelu_f(g0.y));
          tmp[2] = (short)f2bf(a0.z * gelu_f(g0.z));
          tmp[3] = (short)f2bf(a0.w * gelu_f(g0.w));
          tmp[4] = (short)f2bf(a1.x * gelu_f(g1.x));
          tmp[5] = (short)f2bf(a1.y * gelu_f(g1.y));
          tmp[6] = (short)f2bf(a1.z * gelu_f(g1.z));
          tmp[7] = (short)f2bf(a1.w * gelu_f(g1.w));
          *(bf16x8*)&As[am][ak] = *(bf16x8*)tmp;
        } else if (AMODE == 2) {
          float4 a0 = aF[r][0], a1 = aF[r][1];
          short tmp[8];
          tmp[0] = (short)f2bf(a0.x); tmp[1] = (short)f2bf(a0.y);
          tmp[2] = (short)f2bf(a0.z); tmp[3] = (short)f2bf(a0.w);
          tmp[4] = (short)f2bf(a1.x); tmp[5] = (short)f2bf(a1.y);
          tmp[6] = (short)f2bf(a1.z); tmp[7] = (short)f2bf(a1.w);
          *(bf16x8*)&As[am][ak] = *(bf16x8*)tmp;
        } else {
          float4 a0 = aF[r][0], a1 = aF[r][1];
          int kb = kc + r * 64 + ak;
          short tmp[8];
          tmp[0] = (short)f2bf((a0.x - mm) * rstd * sG[kb + 0] + sB2[kb + 0]);
          tmp[1] = (short)f2bf((a0.y - mm) * rstd * sG[kb + 1] + sB2[kb + 1]);
          tmp[2] = (short)f2bf((a0.z - mm) * rstd * sG[kb + 2] + sB2[kb + 2]);
          tmp[3] = (short)f2bf((a0.w - mm) * rstd * sG[kb + 3] + sB2[kb + 3]);
          tmp[4] = (short)f2bf((a1.x - mm) * rstd * sG[kb + 4] + sB2[kb + 4]);
          tmp[5] = (short)f2bf((a1.y - mm) * rstd * sG[kb + 5] + sB2[kb + 5]);
          tmp[6] = (short)f2bf((a1.z - mm) * rstd * sG[kb + 6] + sB2[kb + 6]);
          tmp[7] = (short)f2bf((a1.w - mm) * rstd * sG[kb + 7] + sB2[kb + 7]);
          *(bf16x8*)&As[am][ak] = *(bf16x8*)tmp;
        }
      }
      {
        bf16x8 bv0 = bR[r][0], bv1 = bR[r][1];
#pragma unroll
        for (int i2 = 0; i2 < 8; ++i2) Bs[bn + i2][bk] = bv0[i2];
#pragma unroll
        for (int i2 = 0; i2 < 8; ++i2) Bs[bn + 8 + i2][bk] = bv1[i2];
      }
      __syncthreads();
      int q = lane >> 4;
      bf16x8 af0 = *(const bf16x8*)&As[lane & 15][q * 8];
      bf16x8 af1 = *(const bf16x8*)&As[lane & 15][32 + q * 8];
      bf16x8 bf0 = *(const bf16x8*)&Bs[w * 16 + (lane & 15)][q * 8];
      bf16x8 bf1 = *(const bf16x8*)&Bs[w * 16 + (lane & 15)][32 + q * 8];
      acc = __builtin_amdgcn_mfma_f32_16x16x32_bf16(af0, bf0, acc, 0, 0, 0);
      acc = __builtin_amdgcn_mfma_f32_16x16x32_bf16(af1, bf1, acc, 0, 0, 0);
      __syncthreads();
    }
  }

  int q = lane >> 4;
  int cn = w * 16 + (lane & 15);
  int col = n0C + cn;
  float bv = bias ? bias[n0B + cn] : 0.0f;
#pragma unroll
  for (int rr = 0; rr < 4; ++rr) {
    int row = m0 + q * 4 + rr;
    float v = acc[rr] + bv;
    if (resid) v += resid[(size_t)row * ldc + col];
    if (OMODE == 2 || (OMODE == 1 && obf)) {
      ((unsigned short*)C)[(size_t)row * ldc + col] = f2bf(v);
    } else {
      ((float*)C)[(size_t)row * ldc + col] = v;
    }
  }
}

template <int AMODE, int OMODE>
__global__ __launch_bounds__(256) void k_mfma(const void* A, int lda, int aYoffBytes,
                                              const unsigned short* B, int ldb,
                                              const float* bias, const float* resid,
                                              void* C, int ldc, int K,
                                              const unsigned* probe,
                                              const float* lnG, const float* lnB) {
  bool obf = (OMODE == 1) && probe && (*probe != 0x3F800000u);
  int n0 = blockIdx.y * 64;
  const void* Ap = (const char*)A + (size_t)aYoffBytes * blockIdx.y;
  mfma_body<AMODE, OMODE>(Ap, lda, B, ldb, n0, bias, resid, C, ldc, n0,
                          blockIdx.x * 16, K, obf, lnG, lnB);
}

// QKV with fused LN: Wq/Wk/Wv sections are 131072 elems apart in the bf16 blob.
__global__ __launch_bounds__(256) void k_mfma_qkv(const float* X,
                                                  const float* lnG, const float* lnB,
                                                  const unsigned short* WqL, float* qkv) {
  int sel = blockIdx.y >> 2;
  const unsigned short* B = WqL + sel * 131072;
  int n0B = (blockIdx.y & 3) * 64;
  int n0C = blockIdx.y * 64;
  mfma_body<3, 0>(X, 256, B, 256, n0B, nullptr, nullptr, qkv, 768, n0C,
                  blockIdx.x * 16, 256, false, lnG, lnB);
}

// ---------- simz: sim + exp + rowsum atomics (edge-parallel) ----------
// Blocks 0..3 additionally zero the hub rows' tbx slots (r = bx*256).
__global__ __launch_bounds__(256) void k_simz(const float* __restrict__ cf,
                                              const float* __restrict__ qkv,
                                              const int* __restrict__ rowof,
                                              const int* __restrict__ colsb,
                                              const int* __restrict__ gctr,
                                              const float* __restrict__ lsbuf,
                                              const float* __restrict__ ebW1,
                                              const float* __restrict__ ebB1,
                                              const float* __restrict__ ebW2,
                                              const float* __restrict__ ebB2,
                                              float* __restrict__ esim,
                                              float* __restrict__ rowsum,
                                              float* __restrict__ tbx) {
  int t = threadIdx.x;
  if (blockIdx.x < 4) {
    int hr = blockIdx.x * 256;
    size_t tz = (size_t)hr * 1280 + t;
    tbx[tz] = 0.f; tbx[tz + 256] = 0.f; tbx[tz + 512] = 0.f;
    tbx[tz + 768] = 0.f; tbx[tz + 1024] = 0.f;
  }
  int E = *gctr;
  int lane = t & 63, w = t >> 6;
  float W1r[4][10], B1r[4], W2r[4][4];
#pragma unroll
  for (int kk = 0; kk < 4; ++kk) {
    int c = kk * 64 + lane;
    B1r[kk] = ebB1[c];
#pragma unroll
    for (int f = 0; f < 10; ++f) W1r[kk][f] = ebW1[f * 256 + c];
    float4 w2 = *(const float4*)(ebW2 + c * 4);
    W2r[kk][0] = w2.x; W2r[kk][1] = w2.y; W2r[kk][2] = w2.z; W2r[kk][3] = w2.w;
  }
  float b20 = ebB2[0], b21 = ebB2[1], b22 = ebB2[2], b23 = ebB2[3];
  for (int g = blockIdx.x * 4 + w; g < E; g += 4096) {
    int r = rowof[g], j = colsb[g];
    int b = r >> 8, i = r & 255;
    float ls = lsbuf[b];
    const float2* cc = (const float2*)cf;
    float2 ci = cc[b * 256 + i], cj = cc[b * 256 + j];
    float ef[10];
    edge_feats(i, j, ci.x, ci.y, cj.x, cj.y, ls, ef);
    float red[8];
#pragma unroll
    for (int z = 0; z < 8; ++z) red[z] = 0.0f;
#pragma unroll
    for (int kk = 0; kk < 4; ++kk) {
      int c = kk * 64 + lane;
      float h1 = B1r[kk];
#pragma unroll
      for (int f = 0; f < 10; ++f) h1 += ef[f] * W1r[kk][f];
      float g1 = gelu_f(h1);
      red[4] += g1 * W2r[kk][0];
      red[5] += g1 * W2r[kk][1];
      red[6] += g1 * W2r[kk][2];
      red[7] += g1 * W2r[kk][3];
      red[kk] = qkv[(size_t)r * 768 + c] * qkv[((size_t)(b * 256 + j)) * 768 + 256 + c];
    }
#pragma unroll
    for (int z = 0; z < 8; ++z) {
#pragma unroll
      for (int o = 32; o > 0; o >>= 1) red[z] += __shfl_xor(red[z], o);
    }
    if (lane == 0) {
      float e0 = expf(red[0] * 0.125f + red[4] + b20);
      float e1 = expf(red[1] * 0.125f + red[5] + b21);
      float e2 = expf(red[2] * 0.125f + red[6] + b22);
      float e3 = expf(red[3] * 0.125f + red[7] + b23);
      *(float4*)&esim[(size_t)g * 4] = make_float4(e0, e1, e2, e3);
      atomicAdd(&rowsum[r * 4 + 0], e0);
      atomicAdd(&rowsum[r * 4 + 1], e1);
      atomicAdd(&rowsum[r * 4 + 2], e2);
      atomicAdd(&rowsum[r * 4 + 3], e3);
    }
  }
}

// ---------- accum: hybrid chunked (32-edge chunks) -> tbx [t0|t1|t2|t3|vs] ----
// grid = 1052: x<1024 -> (row x, chunk 0); x>=1024 -> hub rows' chunks 1..7.
__global__ __launch_bounds__(256, 8) void k_accum(const float* __restrict__ cf,
                                                  const float* __restrict__ qkv,
                                                  const int* __restrict__ rowptr,
                                                  const int* __restrict__ deg,
                                                  const int* __restrict__ colsb,
                                                  const float* __restrict__ esim,
                                                  const float* __restrict__ rowsum,
                                                  const float* __restrict__ lsbuf,
                                                  const float* __restrict__ evW1,
                                                  const float* __restrict__ evB1,
                                                  float* __restrict__ tbx) {
  int x = blockIdx.x;
  int r, ch;
  if (x < 1024) { r = x; ch = 0; }
  else { int i5 = x - 1024; r = (i5 / 7) * 256; ch = 1 + i5 % 7; }
  int d = deg[r];
  int e0 = ch * 32;
  if (e0 >= d) return;
  int n = min(32, d - e0);
  bool whole = (ch == 0) && (d <= 32);
  int base = rowptr[r] + e0;
  int b = r >> 8, i = r & 255;
  int u = threadIdx.x, h = u >> 6;

  __shared__ int scols[32];
  __shared__ float4 sattn[32];
  __shared__ float sef[32][10];
  if (u < n) {
    float4 S4 = *(const float4*)&rowsum[r * 4];
    int j = colsb[base + u];
    scols[u] = j;
    float4 e = *(const float4*)&esim[(size_t)(base + u) * 4];
    sattn[u] = make_float4(e.x / S4.x, e.y / S4.y, e.z / S4.z, e.w / S4.w);
    float ls = lsbuf[b];
    const float2* cc = (const float2*)cf;
    float2 ci = cc[b * 256 + i], cj = cc[b * 256 + j];
    float ef[10];
    edge_feats(i, j, ci.x, ci.y, cj.x, cj.y, ls, ef);
#pragma unroll
    for (int f = 0; f < 10; ++f) sef[u][f] = ef[f];
  }
  __syncthreads();

  float evb = evB1[u];
  float w1r[10];
#pragma unroll
  for (int f = 0; f < 10; ++f) w1r[f] = evW1[f * 256 + u];
  float t0 = 0.f, t1 = 0.f, t2 = 0.f, t3 = 0.f, va = 0.f;
#pragma unroll 4
  for (int e = 0; e < n; ++e) {
    float4 a = sattn[e];
    int j = scols[e];
    float h1 = evb;
#pragma unroll
    for (int f = 0; f < 10; ++f) h1 += sef[e][f] * w1r[f];
    float g1 = gelu_f(h1);
    t0 += a.x * g1; t1 += a.y * g1; t2 += a.z * g1; t3 += a.w * g1;
    float ah = (h == 0) ? a.x : (h == 1) ? a.y : (h == 2) ? a.z : a.w;
    va += ah * qkv[((size_t)(b * 256 + j)) * 768 + 512 + u];
  }
  size_t tbase = (size_t)r * 1280 + u;
  if (whole) {
    tbx[tbase]        = t0;
    tbx[tbase + 256]  = t1;
    tbx[tbase + 512]  = t2;
    tbx[tbase + 768]  = t3;
    tbx[tbase + 1024] = va;
  } else {
    atomicAdd(&tbx[tbase], t0);
    atomicAdd(&tbx[tbase + 256], t1);
    atomicAdd(&tbx[tbase + 512], t2);
    atomicAdd(&tbx[tbase + 768], t3);
    atomicAdd(&tbx[tbase + 1024], va);
  }
}

extern "C" void kernel_launch(void* const* d_in, const int* in_sizes, int n_in,
                              void* d_out, int out_size, void* d_ws, size_t ws_size,
                              hipStream_t stream) {
  (void)in_sizes; (void)n_in; (void)out_size; (void)ws_size;

  char* wp = (char*)d_ws;
  auto carve = [&](size_t bytes) -> char* {
    char* p = wp;
    wp += ((bytes + 255) / 256) * 256;
    return p;
  };
  int*   gctr   = (int*)carve(4);
  float* lsb    = (float*)carve(16);
  int*   valid  = (int*)carve(1024 * 4);
  int*   deg    = (int*)carve(1024 * 4);
  int*   rowptr = (int*)carve(1024 * 4);
  int*   rowof  = (int*)carve(MAXE * 4);
  int*   colsb  = (int*)carve(MAXE * 4);
  int*   knn    = (int*)carve(1024 * 3 * 4);
  float* rowsum = (float*)carve(8192 * 4);
  float* sim    = (float*)carve((size_t)MAXE * 16);
  float* blobF  = (float*)carve((size_t)(262144 + NONX) * 4);
  unsigned short* blobB = (unsigned short*)carve((size_t)BF16_TOTAL * 2);
  unsigned short* Bcat  = (unsigned short*)carve((size_t)2 * 327680 * 2);
  float* bias2  = (float*)carve(512 * 4);
  float* qkv    = (float*)carve((size_t)1024 * 768 * 4);
  float* xcur   = (float*)carve((size_t)262144 * 4);
  float* tbx    = (float*)carve((size_t)1024 * 1280 * 4);  // [t0|t1|t2|t3|vs]
  float* tb     = (float*)carve((size_t)1048576 * 4);      // FF hidden

  // fp32 blob pointers
  const float* Xf    = blobF + 0;
  const float* Cf    = blobF + 262144;
  const float* ebW1  = blobF + 264192;
  const float* ebB1  = blobF + 269824;
  const float* ebW2  = blobF + 270336;
  const float* ebB2  = blobF + 272384;
  const float* evW1  = blobF + 272448;
  const float* evB1  = blobF + 278080;
  const float* evB2  = blobF + 278592;
  const float* boB   = blobF + 279104;
  const float* ln1w  = blobF + 279616;
  const float* ln1b  = blobF + 280128;
  const float* ln2w  = blobF + 280640;
  const float* ln2b  = blobF + 281152;
  const float* ffb1  = blobF + 281664;
  const float* ffb2  = blobF + 283712;
  // bf16 blob pointers
  const unsigned short* WqB   = blobB + 0;
  const unsigned short* WoB   = blobB + 393216;
  const unsigned short* evW2B = blobB + 524288;
  const unsigned short* ffw1B = blobB + 655360;
  const unsigned short* ffw2B = blobB + 1179648;

  PtrPack pp;
  for (int i = 0; i < 23; ++i) pp.p[i] = d_in[i];
  const unsigned* probe = (const unsigned*)d_in[15];

  k_convert<<<2048, 256, 0, stream>>>(pp, blobF, blobB, valid, rowsum, gctr);
  k_knn_prep<<<330, 256, 0, stream>>>(Cf, valid, knn, evW2B, WoB, evB2, boB, Bcat, bias2);
  k_csr<<<4, 256, 0, stream>>>(Cf, valid, knn, lsb, deg, rowptr, rowof, colsb, gctr);

  for (int l = 0; l < 2; ++l) {
    const float* xsrc = (l == 0) ? Xf : xcur;
    float* rsumL = rowsum + l * 4096;
    k_mfma_qkv<<<dim3(64, 12), 256, 0, stream>>>(xsrc, ln1w + l * 256, ln1b + l * 256,
                                                 WqB + l * 65536, qkv);
    k_simz<<<1024, 256, 0, stream>>>(Cf, qkv, rowof, colsb, gctr, lsb,
                                     ebW1 + l * 2816, ebB1 + l * 256,
                                     ebW2 + l * 1024, ebB2 + l * 4,
                                     sim, rsumL, tbx);
    k_accum<<<1052, 256, 0, stream>>>(Cf, qkv, rowptr, deg, colsb, sim, rsumL, lsb,
                                      evW1 + l * 2816, evB1 + l * 256, tbx);
    // fused epi+Wo GEMM: xcur = [t0|t1|t2|t3|vs] @ [W2o;Wo] + bias2 + xsrc
    k_mfma<2, 0><<<dim3(64, 4), 256, 0, stream>>>(tbx, 1280, 0, Bcat + l * 327680, 256,
                                                  bias2 + l * 256, xsrc, xcur, 256, 1280,
                                                  nullptr, nullptr, nullptr);
    // FF1 with fused LN2
    k_mfma<3, 0><<<dim3(64, 16), 256, 0, stream>>>(xcur, 256, 0, ffw1B + l * 262144, 1024,
                                                   ffb1 + l * 1024, nullptr, tb, 1024, 256,
                                                   nullptr, ln2w + l * 256, ln2b + l * 256);
    // FF2 gated + residual
    if (l == 0) {
      k_mfma<1, 0><<<dim3(64, 4), 256, 0, stream>>>(tb, 1024, 0, ffw2B + l * 131072, 256,
                                                    ffb2 + l * 256, xcur, xcur, 256, 512,
                                                    nullptr, nullptr, nullptr);
    } else {
      k_mfma<1, 1><<<dim3(64, 4), 256, 0, stream>>>(tb, 1024, 0, ffw2B + l * 131072, 256,
                                                    ffb2 + l * 256, xcur, d_out, 256, 512,
                                                    probe, nullptr, nullptr);
    }
  }
}

// Round 10
// 301.456 us; speedup vs baseline: 1.2650x; 1.1047x over previous
//
#include <hip/hip_runtime.h>

// LocalGraphTransformerEncoder on MI355X (gfx950). Round 16.
// R15: 333us -- k_knn_prep 41.9us @3.5% occ: W2o on 64 blocks with a 2048-
// iter serial ds_read_u16 chain (same narrow-width error class as R14 csr).
// R16: W2o re-parallelized: 128 blocks (l,h,16-row grp); W2 tile (2KB) in
// LDS via ushort4, Wo column in 64 REGISTERS (coalesced), inner loop = LDS
// b128 broadcasts + unrolled FMA (static indices). Grid 256 kNN + 138 prep.
// Keep epi+Wo K=1280 fusion. Dispatches 15.
// Standing lessons: no persistent grid barriers (R8/R9); sim edge-parallel
// (R11); accum chunk <=32 (R12); never shrink a phase's parallel width to
// save a dispatch (R14/R15).

#define MAXE  16384
#define NONX  22080
#define BF16_TOTAL 1441792

typedef __attribute__((ext_vector_type(8))) short bf16x8;
typedef __attribute__((ext_vector_type(4))) float f32x4;

struct PtrPack { const void* p[23]; };

__device__ __forceinline__ float bf2f(unsigned short s) {
  return __uint_as_float(((unsigned)s) << 16);
}
__device__ __forceinline__ unsigned short f2bf(float f) {
  unsigned u = __float_as_uint(f);
  u += 0x7fffu + ((u >> 16) & 1u);
  return (unsigned short)(u >> 16);
}
__device__ __forceinline__ float gelu_f(float x) {
  return 0.5f * x * (1.0f + erff(x * 0.70710678118654752440f));
}
__device__ __forceinline__ float wave_red_sum(float v) {
#pragma unroll
  for (int o = 32; o > 0; o >>= 1) v += __shfl_xor(v, o);
  return v;
}

__device__ __forceinline__ void edge_feats(int i, int j, float cxi, float cyi,
                                           float cxj, float cyj, float lsd, float* e) {
  float dx = cxj - cxi, dy = cyj - cyi;
  float dist = sqrtf(dx * dx + dy * dy + 1e-8f);
  e[0] = dx; e[1] = dy; e[2] = dist; e[3] = dist / lsd;
  bool qic = (i == 0), kic = (j == 0), eye = (i == j);
  e[4] = qic ? 1.f : 0.f;
  e[5] = kic ? 1.f : 0.f;
  e[6] = eye ? 1.f : 0.f;
  e[7] = (!qic && !kic && !eye) ? 1.f : 0.f;
  int hi = (i == 0) ? 0 : ((i < 128) ? 1 : 2);
  int hj = (j == 0) ? 0 : ((j < 128) ? 1 : 2);
  e[8] = (hi == hj) ? 1.f : 0.f;
  int hd = hj - hi;
  e[9] = (float)(hd < 0 ? -hd : hd);
}

// ---------- convert: fp32 smalls + bf16 weights + valid + rowsum zero ----------
__global__ __launch_bounds__(256) void k_convert(PtrPack pp, float* __restrict__ blobF,
                                                 unsigned short* __restrict__ blobB,
                                                 int* __restrict__ valid,
                                                 float* __restrict__ rowsum,
                                                 int* __restrict__ gctr) {
  bool isf32 = (*(const unsigned*)pp.p[15] == 0x3F800000u);
  int t = threadIdx.x;
  if (blockIdx.x == 0 && t == 0) *gctr = 0;
  if (blockIdx.x < 1024) {
    if (blockIdx.x < 32) rowsum[blockIdx.x * 256 + t] = 0.f;
    int r = blockIdx.x;
    int idx = r * 256 + t;
    float v = isf32 ? ((const float*)pp.p[0])[idx]
                    : bf2f(((const unsigned short*)pp.p[0])[idx]);
    blobF[idx] = v;
    __shared__ float s[4];
    float a = wave_red_sum(fabsf(v));
    if ((t & 63) == 0) s[t >> 6] = a;
    __syncthreads();
    if (t == 0) valid[r] = ((s[0] + s[1] + s[2] + s[3]) > 0.0f) || ((r & 255) == 0);
  } else {
    const int fst[16] = {0,2048,7680,8192,10240,10304,15936,16448,16960,17472,17984,18496,19008,19520,21568,22080};
    const int fsz[15] = {2048,5632,512,2048,8,5632,512,512,512,512,512,512,512,2048,512};
    const int fin[15] = {1,5,6,7,8,9,10,12,14,15,16,17,18,20,22};
    const int bst[8]  = {0,131072,262144,393216,524288,655360,1179648,1441792};
    const int bin[7]  = {2,3,4,13,11,19,21};
    const int NUNITS = NONX + BF16_TOTAL / 4;   // bf16 handled 4-at-a-time
    for (int u = (blockIdx.x - 1024) * 256 + t; u < NUNITS; u += 1024 * 256) {
      if (u < NONX) {
        int s = 0;
        while (s < 14 && u >= fst[s + 1]) ++s;
        int e = u - fst[s];
        float v = 0.f;
        if (e < fsz[s]) v = isf32 ? ((const float*)pp.p[fin[s]])[e]
                                  : bf2f(((const unsigned short*)pp.p[fin[s]])[e]);
        blobF[262144 + u] = v;
      } else {
        int bi = (u - NONX) * 4;       // quad of bf16 elems; sections 64-aligned
        int s = 0;
        while (s < 6 && bi >= bst[s + 1]) ++s;
        int e = bi - bst[s];
        ushort4 o;
        if (isf32) {
          const float* sp = (const float*)pp.p[bin[s]] + e;
          o.x = f2bf(sp[0]); o.y = f2bf(sp[1]); o.z = f2bf(sp[2]); o.w = f2bf(sp[3]);
        } else {
          o = *(const ushort4*)((const unsigned short*)pp.p[bin[s]] + e);
        }
        *(ushort4*)&blobB[bi] = o;
      }
    }
  }
}

// ---------- kNN (wave-parallel) + prep (wide) in one dispatch ----------
// blocks 0..255: kNN. 256..383: W2o (l,h,16-row group, Wo col in regs).
// 384,385: bias2. 386..393: Wo copy into Bcat rows 1024..1279.
__global__ __launch_bounds__(256) void k_knn_prep(const float* __restrict__ cf,
                                                  const int* __restrict__ valid,
                                                  int* __restrict__ knn,
                                                  const unsigned short* __restrict__ evW2B,
                                                  const unsigned short* __restrict__ WoB,
                                                  const float* __restrict__ evB2,
                                                  const float* __restrict__ boB,
                                                  unsigned short* __restrict__ Bcat,
                                                  float* __restrict__ bias2) {
  int blk = blockIdx.x;
  if (blk < 256) {
    int b = blk >> 6;
    int w = threadIdx.x >> 6, lane = threadIdx.x & 63;
    int i = (blk & 63) * 4 + w;
    const float2* cc = (const float2*)(cf + b * 512);
    float2 ci = cc[i];
    bool vi = (valid[b * 256 + i] != 0) && (i != 0);
    unsigned long long key[4];
#pragma unroll
    for (int k = 0; k < 4; ++k) {
      int j = lane + 64 * k;
      bool ok = vi && (j != 0) && (j != i) && (valid[b * 256 + j] != 0);
      unsigned long long kk = ~0ull;
      if (ok) {
        float2 cj = cc[j];
        float dx = ci.x - cj.x, dy = ci.y - cj.y;
        float dd = sqrtf(dx * dx + dy * dy);
        kk = (((unsigned long long)__float_as_uint(dd)) << 32) | (unsigned)j;
      }
      key[k] = kk;
    }
    int out[3];
#pragma unroll
    for (int rnd = 0; rnd < 3; ++rnd) {
      unsigned long long m = key[0];
      if (key[1] < m) m = key[1];
      if (key[2] < m) m = key[2];
      if (key[3] < m) m = key[3];
#pragma unroll
      for (int o = 32; o > 0; o >>= 1) {
        unsigned long long om = __shfl_xor(m, o);
        if (om < m) m = om;
      }
      out[rnd] = (m != ~0ull) ? (int)(m & 0xFFFFFFFFull) : -1;
#pragma unroll
      for (int k = 0; k < 4; ++k)
        if (key[k] == m) key[k] = ~0ull;
    }
    if (lane == 0) {
      knn[(b * 256 + i) * 3 + 0] = out[0];
      knn[(b * 256 + i) * 3 + 1] = out[1];
      knn[(b * 256 + i) * 3 + 2] = out[2];
    }
  } else if (blk < 384) {
    // W2o: block = (l, h, ug); 16 u-rows x 256 n cols; K=64.
    int x = blk - 256;
    int l = x >> 6, rem = x & 63;
    int h = rem >> 4, ug = rem & 15;
    int u0 = ug * 16, n = threadIdx.x;
    const unsigned short* W2 = evW2B + l * 65536;
    const unsigned short* Wo = WoB + l * 65536;
    __shared__ short sW2[1024];            // 16 rows x 64 dh (bf16)
    {
      int idx = n * 4;                     // 4 shorts per thread
      int uu = idx >> 6, dh = idx & 63;
      ushort4 v = *(const ushort4*)(W2 + (u0 + uu) * 256 + h * 64 + dh);
      *(ushort4*)&sW2[idx] = *(ushort4*)&v;
    }
    float wo[64];
#pragma unroll
    for (int dh = 0; dh < 64; ++dh)
      wo[dh] = bf2f(Wo[(h * 64 + dh) * 256 + n]);
    __syncthreads();
#pragma unroll
    for (int u = 0; u < 16; ++u) {
      float acc = 0.f;
#pragma unroll
      for (int dv = 0; dv < 8; ++dv) {
        bf16x8 w2v = *(const bf16x8*)&sW2[u * 64 + dv * 8];
#pragma unroll
        for (int e = 0; e < 8; ++e)
          acc += bf2f((unsigned short)w2v[e]) * wo[dv * 8 + e];
      }
      Bcat[(size_t)l * 327680 + (size_t)(h * 256 + u0 + u) * 256 + n] = f2bf(acc);
    }
  } else if (blk < 386) {
    int l = blk - 384, n = threadIdx.x;
    const unsigned short* Wo = WoB + l * 65536;
    float acc = boB[l * 256 + n];
    for (int c = 0; c < 256; ++c)
      acc += evB2[l * 256 + c] * bf2f(Wo[c * 256 + n]);
    bias2[l * 256 + n] = acc;
  } else {
    int idx = blk - 386, n = threadIdx.x;
    int l = idx >> 2, q = idx & 3;
    const unsigned short* Wo = WoB + l * 65536;
    for (int rr = 0; rr < 64; ++rr) {
      int c = q * 64 + rr;
      Bcat[(size_t)l * 327680 + (size_t)(1024 + c) * 256 + n] = Wo[c * 256 + n];
    }
  }
}

// ---------- CSR build (shuffle scan) ----------
__global__ __launch_bounds__(256) void k_csr(const float* __restrict__ cf,
                                             const int* __restrict__ valid,
                                             const int* __restrict__ knn,
                                             float* __restrict__ lsbuf,
                                             int* __restrict__ deg, int* __restrict__ rowptr,
                                             int* __restrict__ rowof, int* __restrict__ colsb,
                                             int* __restrict__ gctr) {
  int b = blockIdx.x, t = threadIdx.x;
  __shared__ unsigned adjw[256][8];
  __shared__ float sred[8];
  __shared__ int wsum[4];
  __shared__ int sbase;

  int r = b * 256 + t;
  float cx = cf[r * 2 + 0], cy = cf[r * 2 + 1];
  int lv = valid[r];
#pragma unroll
  for (int w = 0; w < 8; ++w) adjw[t][w] = 0u;
  __syncthreads();

  atomicOr(&adjw[t][t >> 5], 1u << (t & 31));
  if (t >= 1 && lv) {
    atomicOr(&adjw[0][t >> 5], 1u << (t & 31));
    atomicOr(&adjw[t][0], 1u);
  }
#pragma unroll
  for (int s = 0; s < 3; ++s) {
    int j = knn[r * 3 + s];
    if (j >= 0) {
      atomicOr(&adjw[t][j >> 5], 1u << (j & 31));
      atomicOr(&adjw[j][t >> 5], 1u << (t & 31));
    }
  }
  float cdist = sqrtf(cx * cx + cy * cy + 1e-8f);
  int nvm = (t >= 1) && lv;
  float rs = wave_red_sum(nvm ? cdist : 0.0f);
  float rc = wave_red_sum(nvm ? 1.0f : 0.0f);
  if ((t & 63) == 0) { sred[t >> 6] = rs; sred[4 + (t >> 6)] = rc; }
  __syncthreads();

  if (t == 0) {
    float totd = sred[0] + sred[1] + sred[2] + sred[3];
    float totc = sred[4] + sred[5] + sred[6] + sred[7];
    float ls = totd / fmaxf(totc, 1.0f);
    ls = (ls > 0.0f) ? ls : 1.0f;
    lsbuf[b] = fmaxf(ls, 1e-6f);
  }

  int dg = 0;
#pragma unroll
  for (int w = 0; w < 8; ++w) dg += __popc(adjw[t][w]);

  int lane = t & 63, wv = t >> 6;
  int x = dg;
#pragma unroll
  for (int off = 1; off < 64; off <<= 1) {
    int y = __shfl_up(x, off);
    if (lane >= off) x += y;
  }
  if (lane == 63) wsum[wv] = x;
  __syncthreads();
  if (t == 0) sbase = atomicAdd(gctr, wsum[0] + wsum[1] + wsum[2] + wsum[3]);
  __syncthreads();
  int woff = 0;
#pragma unroll
  for (int k2i = 0; k2i < 4; ++k2i) woff += (k2i < wv) ? wsum[k2i] : 0;
  int off0 = sbase + woff + x - dg;

  rowptr[r] = off0;
  deg[r] = dg;
  int o = off0;
#pragma unroll
  for (int w = 0; w < 8; ++w) {
    unsigned bits = adjw[t][w];
    while (bits) {
      int bp = __ffs(bits) - 1;
      colsb[o] = w * 32 + bp;
      rowof[o] = r;
      ++o;
      bits &= bits - 1;
    }
  }
}

// ---------- bf16 MFMA GEMM body: 16x64 tile, BK=64, full-K reg prefetch ----
// AMODE: 0=bf16 A | 1=gated fp32 (gate +512, lda=1024) | 2=plain fp32 | 3=LN-fused fp32
// OMODE: 0=fp32 | 1=probe bf16/fp32 | 2=bf16
// K must be a multiple of 256. AMODE 3 requires K==256.
template <int AMODE, int OMODE>
__device__ __forceinline__ void mfma_body(const void* Aptr, int lda,
                                          const unsigned short* __restrict__ B, int ldb, int n0B,
                                          const float* __restrict__ bias,
                                          const float* resid,
                                          void* C, int ldc, int n0C,
                                          int m0, int K, bool obf,
                                          const float* __restrict__ lnG,
                                          const float* __restrict__ lnB) {
  __shared__ short As[16][72];
  __shared__ short Bs[64][72];
  __shared__ float sG[256], sB2[256];
  int t = threadIdx.x, lane = t & 63, w = t >> 6;

  int am = t >> 3, ak = (t & 7) * 8;   // A staging (t < 128): 16 rows x 64 k
  int bk = t >> 2, bn = (t & 3) * 16;  // B staging (all): 64 k x 64 n

  f32x4 acc;
  acc[0] = 0.f; acc[1] = 0.f; acc[2] = 0.f; acc[3] = 0.f;

  for (int kc = 0; kc < K; kc += 256) {
    // ---- prefetch 4 rounds of A and B into registers (independent loads) ----
    bf16x8 aB[4];
    float4 aF[4][2];
    float4 gF[4][2];
    bf16x8 bR[4][2];
#pragma unroll
    for (int r = 0; r < 4; ++r) {
      int k0 = kc + r * 64;
      if (t < 128) {
        if (AMODE == 0) {
          aB[r] = *(const bf16x8*)((const unsigned short*)Aptr +
                                   (size_t)(m0 + am) * lda + k0 + ak);
        } else {
          const float* ap = (const float*)Aptr + (size_t)(m0 + am) * lda + k0 + ak;
          aF[r][0] = *(const float4*)ap;
          aF[r][1] = *(const float4*)(ap + 4);
          if (AMODE == 1) {
            gF[r][0] = *(const float4*)(ap + 512);
            gF[r][1] = *(const float4*)(ap + 516);
          }
        }
      }
      const unsigned short* bp = B + (size_t)(k0 + bk) * ldb + n0B + bn;
      bR[r][0] = *(const bf16x8*)bp;
      bR[r][1] = *(const bf16x8*)(bp + 8);
    }

    // ---- AMODE 3: LN gamma/beta to LDS; row stats from prefetched regs ----
    float mm = 0.f, rstd = 0.f;
    if (AMODE == 3) {
      sG[t] = lnG[t]; sB2[t] = lnB[t];
      if (t < 128) {
        float s = 0.f, ss = 0.f;
#pragma unroll
        for (int r = 0; r < 4; ++r)
#pragma unroll
          for (int h2 = 0; h2 < 2; ++h2) {
            float4 v4 = aF[r][h2];
            s += v4.x + v4.y + v4.z + v4.w;
            ss += v4.x * v4.x + v4.y * v4.y + v4.z * v4.z + v4.w * v4.w;
          }
        s += __shfl_xor(s, 1); s += __shfl_xor(s, 2); s += __shfl_xor(s, 4);
        ss += __shfl_xor(ss, 1); ss += __shfl_xor(ss, 2); ss += __shfl_xor(ss, 4);
        mm = s * (1.f / 256.f);
        float var = ss * (1.f / 256.f) - mm * mm;
        rstd = 1.f / sqrtf(var + 1e-5f);
      }
      __syncthreads();
    }

    // ---- 4 rounds: stage from registers, MFMA ----
#pragma unroll
    for (int r = 0; r < 4; ++r) {
      if (t < 128) {
        if (AMODE == 0) {
          *(bf16x8*)&As[am][ak] = aB[r];
        } else if (AMODE == 1) {
          float4 a0 = aF[r][0], a1 = aF[r][1];
          float4 g0 = gF[r][0], g1 = gF[r][1];
          short tmp[8];
          tmp[0] = (short)f2bf(a0.x * gelu_f(g0.x));
          tmp[1] = (short)f2bf(a0.y * gelu_f(g0.y));
          tmp[2] = (short)f2bf(a0.z * gelu_f(g0.z));
          tmp[3] = (short)f2bf(a0.w * gelu_f(g0.w));
          tmp[4] = (short)f2bf(a1.x * gelu_f(g1.x));
          tmp[5] = (short)f2bf(a1.y * gelu_f(g1.y));
          tmp[6] = (short)f2bf(a1.z * gelu_f(g1.z));
          tmp[7] = (short)f2bf(a1.w * gelu_f(g1.w));
          *(bf16x8*)&As[am][ak] = *(bf16x8*)tmp;
        } else if (AMODE == 2) {
          float4 a0 = aF[r][0], a1 = aF[r][1];
          short tmp[8];
          tmp[0] = (short)f2bf(a0.x); tmp[1] = (short)f2bf(a0.y);
          tmp[2] = (short)f2bf(a0.z); tmp[3] = (short)f2bf(a0.w);
          tmp[4] = (short)f2bf(a1.x); tmp[5] = (short)f2bf(a1.y);
          tmp[6] = (short)f2bf(a1.z); tmp[7] = (short)f2bf(a1.w);
          *(bf16x8*)&As[am][ak] = *(bf16x8*)tmp;
        } else {
          float4 a0 = aF[r][0], a1 = aF[r][1];
          int kb = kc + r * 64 + ak;
          short tmp[8];
          tmp[0] = (short)f2bf((a0.x - mm) * rstd * sG[kb + 0] + sB2[kb + 0]);
          tmp[1] = (short)f2bf((a0.y - mm) * rstd * sG[kb + 1] + sB2[kb + 1]);
          tmp[2] = (short)f2bf((a0.z - mm) * rstd * sG[kb + 2] + sB2[kb + 2]);
          tmp[3] = (short)f2bf((a0.w - mm) * rstd * sG[kb + 3] + sB2[kb + 3]);
          tmp[4] = (short)f2bf((a1.x - mm) * rstd * sG[kb + 4] + sB2[kb + 4]);
          tmp[5] = (short)f2bf((a1.y - mm) * rstd * sG[kb + 5] + sB2[kb + 5]);
          tmp[6] = (short)f2bf((a1.z - mm) * rstd * sG[kb + 6] + sB2[kb + 6]);
          tmp[7] = (short)f2bf((a1.w - mm) * rstd * sG[kb + 7] + sB2[kb + 7]);
          *(bf16x8*)&As[am][ak] = *(bf16x8*)tmp;
        }
      }
      {
        bf16x8 bv0 = bR[r][0], bv1 = bR[r][1];
#pragma unroll
        for (int i2 = 0; i2 < 8; ++i2) Bs[bn + i2][bk] = bv0[i2];
#pragma unroll
        for (int i2 = 0; i2 < 8; ++i2) Bs[bn + 8 + i2][bk] = bv1[i2];
      }
      __syncthreads();
      int q = lane >> 4;
      bf16x8 af0 = *(const bf16x8*)&As[lane & 15][q * 8];
      bf16x8 af1 = *(const bf16x8*)&As[lane & 15][32 + q * 8];
      bf16x8 bf0 = *(const bf16x8*)&Bs[w * 16 + (lane & 15)][q * 8];
      bf16x8 bf1 = *(const bf16x8*)&Bs[w * 16 + (lane & 15)][32 + q * 8];
      acc = __builtin_amdgcn_mfma_f32_16x16x32_bf16(af0, bf0, acc, 0, 0, 0);
      acc = __builtin_amdgcn_mfma_f32_16x16x32_bf16(af1, bf1, acc, 0, 0, 0);
      __syncthreads();
    }
  }

  int q = lane >> 4;
  int cn = w * 16 + (lane & 15);
  int col = n0C + cn;
  float bv = bias ? bias[n0B + cn] : 0.0f;
#pragma unroll
  for (int rr = 0; rr < 4; ++rr) {
    int row = m0 + q * 4 + rr;
    float v = acc[rr] + bv;
    if (resid) v += resid[(size_t)row * ldc + col];
    if (OMODE == 2 || (OMODE == 1 && obf)) {
      ((unsigned short*)C)[(size_t)row * ldc + col] = f2bf(v);
    } else {
      ((float*)C)[(size_t)row * ldc + col] = v;
    }
  }
}

template <int AMODE, int OMODE>
__global__ __launch_bounds__(256) void k_mfma(const void* A, int lda, int aYoffBytes,
                                              const unsigned short* B, int ldb,
                                              const float* bias, const float* resid,
                                              void* C, int ldc, int K,
                                              const unsigned* probe,
                                              const float* lnG, const float* lnB) {
  bool obf = (OMODE == 1) && probe && (*probe != 0x3F800000u);
  int n0 = blockIdx.y * 64;
  const void* Ap = (const char*)A + (size_t)aYoffBytes * blockIdx.y;
  mfma_body<AMODE, OMODE>(Ap, lda, B, ldb, n0, bias, resid, C, ldc, n0,
                          blockIdx.x * 16, K, obf, lnG, lnB);
}

// QKV with fused LN: Wq/Wk/Wv sections are 131072 elems apart in the bf16 blob.
__global__ __launch_bounds__(256) void k_mfma_qkv(const float* X,
                                                  const float* lnG, const float* lnB,
                                                  const unsigned short* WqL, float* qkv) {
  int sel = blockIdx.y >> 2;
  const unsigned short* B = WqL + sel * 131072;
  int n0B = (blockIdx.y & 3) * 64;
  int n0C = blockIdx.y * 64;
  mfma_body<3, 0>(X, 256, B, 256, n0B, nullptr, nullptr, qkv, 768, n0C,
                  blockIdx.x * 16, 256, false, lnG, lnB);
}

// ---------- simz: sim + exp + rowsum atomics (edge-parallel) ----------
// Blocks 0..3 additionally zero the hub rows' tbx slots (r = bx*256).
__global__ __launch_bounds__(256) void k_simz(const float* __restrict__ cf,
                                              const float* __restrict__ qkv,
                                              const int* __restrict__ rowof,
                                              const int* __restrict__ colsb,
                                              const int* __restrict__ gctr,
                                              const float* __restrict__ lsbuf,
                                              const float* __restrict__ ebW1,
                                              const float* __restrict__ ebB1,
                                              const float* __restrict__ ebW2,
                                              const float* __restrict__ ebB2,
                                              float* __restrict__ esim,
                                              float* __restrict__ rowsum,
                                              float* __restrict__ tbx) {
  int t = threadIdx.x;
  if (blockIdx.x < 4) {
    int hr = blockIdx.x * 256;
    size_t tz = (size_t)hr * 1280 + t;
    tbx[tz] = 0.f; tbx[tz + 256] = 0.f; tbx[tz + 512] = 0.f;
    tbx[tz + 768] = 0.f; tbx[tz + 1024] = 0.f;
  }
  int E = *gctr;
  int lane = t & 63, w = t >> 6;
  float W1r[4][10], B1r[4], W2r[4][4];
#pragma unroll
  for (int kk = 0; kk < 4; ++kk) {
    int c = kk * 64 + lane;
    B1r[kk] = ebB1[c];
#pragma unroll
    for (int f = 0; f < 10; ++f) W1r[kk][f] = ebW1[f * 256 + c];
    float4 w2 = *(const float4*)(ebW2 + c * 4);
    W2r[kk][0] = w2.x; W2r[kk][1] = w2.y; W2r[kk][2] = w2.z; W2r[kk][3] = w2.w;
  }
  float b20 = ebB2[0], b21 = ebB2[1], b22 = ebB2[2], b23 = ebB2[3];
  for (int g = blockIdx.x * 4 + w; g < E; g += 4096) {
    int r = rowof[g], j = colsb[g];
    int b = r >> 8, i = r & 255;
    float ls = lsbuf[b];
    const float2* cc = (const float2*)cf;
    float2 ci = cc[b * 256 + i], cj = cc[b * 256 + j];
    float ef[10];
    edge_feats(i, j, ci.x, ci.y, cj.x, cj.y, ls, ef);
    float red[8];
#pragma unroll
    for (int z = 0; z < 8; ++z) red[z] = 0.0f;
#pragma unroll
    for (int kk = 0; kk < 4; ++kk) {
      int c = kk * 64 + lane;
      float h1 = B1r[kk];
#pragma unroll
      for (int f = 0; f < 10; ++f) h1 += ef[f] * W1r[kk][f];
      float g1 = gelu_f(h1);
      red[4] += g1 * W2r[kk][0];
      red[5] += g1 * W2r[kk][1];
      red[6] += g1 * W2r[kk][2];
      red[7] += g1 * W2r[kk][3];
      red[kk] = qkv[(size_t)r * 768 + c] * qkv[((size_t)(b * 256 + j)) * 768 + 256 + c];
    }
#pragma unroll
    for (int z = 0; z < 8; ++z) {
#pragma unroll
      for (int o = 32; o > 0; o >>= 1) red[z] += __shfl_xor(red[z], o);
    }
    if (lane == 0) {
      float e0 = expf(red[0] * 0.125f + red[4] + b20);
      float e1 = expf(red[1] * 0.125f + red[5] + b21);
      float e2 = expf(red[2] * 0.125f + red[6] + b22);
      float e3 = expf(red[3] * 0.125f + red[7] + b23);
      *(float4*)&esim[(size_t)g * 4] = make_float4(e0, e1, e2, e3);
      atomicAdd(&rowsum[r * 4 + 0], e0);
      atomicAdd(&rowsum[r * 4 + 1], e1);
      atomicAdd(&rowsum[r * 4 + 2], e2);
      atomicAdd(&rowsum[r * 4 + 3], e3);
    }
  }
}

// ---------- accum: hybrid chunked (32-edge chunks) -> tbx [t0|t1|t2|t3|vs] ----
// grid = 1052: x<1024 -> (row x, chunk 0); x>=1024 -> hub rows' chunks 1..7.
__global__ __launch_bounds__(256, 8) void k_accum(const float* __restrict__ cf,
                                                  const float* __restrict__ qkv,
                                                  const int* __restrict__ rowptr,
                                                  const int* __restrict__ deg,
                                                  const int* __restrict__ colsb,
                                                  const float* __restrict__ esim,
                                                  const float* __restrict__ rowsum,
                                                  const float* __restrict__ lsbuf,
                                                  const float* __restrict__ evW1,
                                                  const float* __restrict__ evB1,
                                                  float* __restrict__ tbx) {
  int x = blockIdx.x;
  int r, ch;
  if (x < 1024) { r = x; ch = 0; }
  else { int i5 = x - 1024; r = (i5 / 7) * 256; ch = 1 + i5 % 7; }
  int d = deg[r];
  int e0 = ch * 32;
  if (e0 >= d) return;
  int n = min(32, d - e0);
  bool whole = (ch == 0) && (d <= 32);
  int base = rowptr[r] + e0;
  int b = r >> 8, i = r & 255;
  int u = threadIdx.x, h = u >> 6;

  __shared__ int scols[32];
  __shared__ float4 sattn[32];
  __shared__ float sef[32][10];
  if (u < n) {
    float4 S4 = *(const float4*)&rowsum[r * 4];
    int j = colsb[base + u];
    scols[u] = j;
    float4 e = *(const float4*)&esim[(size_t)(base + u) * 4];
    sattn[u] = make_float4(e.x / S4.x, e.y / S4.y, e.z / S4.z, e.w / S4.w);
    float ls = lsbuf[b];
    const float2* cc = (const float2*)cf;
    float2 ci = cc[b * 256 + i], cj = cc[b * 256 + j];
    float ef[10];
    edge_feats(i, j, ci.x, ci.y, cj.x, cj.y, ls, ef);
#pragma unroll
    for (int f = 0; f < 10; ++f) sef[u][f] = ef[f];
  }
  __syncthreads();

  float evb = evB1[u];
  float w1r[10];
#pragma unroll
  for (int f = 0; f < 10; ++f) w1r[f] = evW1[f * 256 + u];
  float t0 = 0.f, t1 = 0.f, t2 = 0.f, t3 = 0.f, va = 0.f;
#pragma unroll 4
  for (int e = 0; e < n; ++e) {
    float4 a = sattn[e];
    int j = scols[e];
    float h1 = evb;
#pragma unroll
    for (int f = 0; f < 10; ++f) h1 += sef[e][f] * w1r[f];
    float g1 = gelu_f(h1);
    t0 += a.x * g1; t1 += a.y * g1; t2 += a.z * g1; t3 += a.w * g1;
    float ah = (h == 0) ? a.x : (h == 1) ? a.y : (h == 2) ? a.z : a.w;
    va += ah * qkv[((size_t)(b * 256 + j)) * 768 + 512 + u];
  }
  size_t tbase = (size_t)r * 1280 + u;
  if (whole) {
    tbx[tbase]        = t0;
    tbx[tbase + 256]  = t1;
    tbx[tbase + 512]  = t2;
    tbx[tbase + 768]  = t3;
    tbx[tbase + 1024] = va;
  } else {
    atomicAdd(&tbx[tbase], t0);
    atomicAdd(&tbx[tbase + 256], t1);
    atomicAdd(&tbx[tbase + 512], t2);
    atomicAdd(&tbx[tbase + 768], t3);
    atomicAdd(&tbx[tbase + 1024], va);
  }
}

extern "C" void kernel_launch(void* const* d_in, const int* in_sizes, int n_in,
                              void* d_out, int out_size, void* d_ws, size_t ws_size,
                              hipStream_t stream) {
  (void)in_sizes; (void)n_in; (void)out_size; (void)ws_size;

  char* wp = (char*)d_ws;
  auto carve = [&](size_t bytes) -> char* {
    char* p = wp;
    wp += ((bytes + 255) / 256) * 256;
    return p;
  };
  int*   gctr   = (int*)carve(4);
  float* lsb    = (float*)carve(16);
  int*   valid  = (int*)carve(1024 * 4);
  int*   deg    = (int*)carve(1024 * 4);
  int*   rowptr = (int*)carve(1024 * 4);
  int*   rowof  = (int*)carve(MAXE * 4);
  int*   colsb  = (int*)carve(MAXE * 4);
  int*   knn    = (int*)carve(1024 * 3 * 4);
  float* rowsum = (float*)carve(8192 * 4);
  float* sim    = (float*)carve((size_t)MAXE * 16);
  float* blobF  = (float*)carve((size_t)(262144 + NONX) * 4);
  unsigned short* blobB = (unsigned short*)carve((size_t)BF16_TOTAL * 2);
  unsigned short* Bcat  = (unsigned short*)carve((size_t)2 * 327680 * 2);
  float* bias2  = (float*)carve(512 * 4);
  float* qkv    = (float*)carve((size_t)1024 * 768 * 4);
  float* xcur   = (float*)carve((size_t)262144 * 4);
  float* tbx    = (float*)carve((size_t)1024 * 1280 * 4);  // [t0|t1|t2|t3|vs]
  float* tb     = (float*)carve((size_t)1048576 * 4);      // FF hidden

  // fp32 blob pointers
  const float* Xf    = blobF + 0;
  const float* Cf    = blobF + 262144;
  const float* ebW1  = blobF + 264192;
  const float* ebB1  = blobF + 269824;
  const float* ebW2  = blobF + 270336;
  const float* ebB2  = blobF + 272384;
  const float* evW1  = blobF + 272448;
  const float* evB1  = blobF + 278080;
  const float* evB2  = blobF + 278592;
  const float* boB   = blobF + 279104;
  const float* ln1w  = blobF + 279616;
  const float* ln1b  = blobF + 280128;
  const float* ln2w  = blobF + 280640;
  const float* ln2b  = blobF + 281152;
  const float* ffb1  = blobF + 281664;
  const float* ffb2  = blobF + 283712;
  // bf16 blob pointers
  const unsigned short* WqB   = blobB + 0;
  const unsigned short* WoB   = blobB + 393216;
  const unsigned short* evW2B = blobB + 524288;
  const unsigned short* ffw1B = blobB + 655360;
  const unsigned short* ffw2B = blobB + 1179648;

  PtrPack pp;
  for (int i = 0; i < 23; ++i) pp.p[i] = d_in[i];
  const unsigned* probe = (const unsigned*)d_in[15];

  k_convert<<<2048, 256, 0, stream>>>(pp, blobF, blobB, valid, rowsum, gctr);
  k_knn_prep<<<394, 256, 0, stream>>>(Cf, valid, knn, evW2B, WoB, evB2, boB, Bcat, bias2);
  k_csr<<<4, 256, 0, stream>>>(Cf, valid, knn, lsb, deg, rowptr, rowof, colsb, gctr);

  for (int l = 0; l < 2; ++l) {
    const float* xsrc = (l == 0) ? Xf : xcur;
    float* rsumL = rowsum + l * 4096;
    k_mfma_qkv<<<dim3(64, 12), 256, 0, stream>>>(xsrc, ln1w + l * 256, ln1b + l * 256,
                                                 WqB + l * 65536, qkv);
    k_simz<<<1024, 256, 0, stream>>>(Cf, qkv, rowof, colsb, gctr, lsb,
                                     ebW1 + l * 2816, ebB1 + l * 256,
                                     ebW2 + l * 1024, ebB2 + l * 4,
                                     sim, rsumL, tbx);
    k_accum<<<1052, 256, 0, stream>>>(Cf, qkv, rowptr, deg, colsb, sim, rsumL, lsb,
                                      evW1 + l * 2816, evB1 + l * 256, tbx);
    // fused epi+Wo GEMM: xcur = [t0|t1|t2|t3|vs] @ [W2o;Wo] + bias2 + xsrc
    k_mfma<2, 0><<<dim3(64, 4), 256, 0, stream>>>(tbx, 1280, 0, Bcat + l * 327680, 256,
                                                  bias2 + l * 256, xsrc, xcur, 256, 1280,
                                                  nullptr, nullptr, nullptr);
    // FF1 with fused LN2
    k_mfma<3, 0><<<dim3(64, 16), 256, 0, stream>>>(xcur, 256, 0, ffw1B + l * 262144, 1024,
                                                   ffb1 + l * 1024, nullptr, tb, 1024, 256,
                                                   nullptr, ln2w + l * 256, ln2b + l * 256);
    // FF2 gated + residual
    if (l == 0) {
      k_mfma<1, 0><<<dim3(64, 4), 256, 0, stream>>>(tb, 1024, 0, ffw2B + l * 131072, 256,
                                                    ffb2 + l * 256, xcur, xcur, 256, 512,
                                                    nullptr, nullptr, nullptr);
    } else {
      k_mfma<1, 1><<<dim3(64, 4), 256, 0, stream>>>(tb, 1024, 0, ffw2B + l * 131072, 256,
                                                    ffb2 + l * 256, xcur, d_out, 256, 512,
                                                    probe, nullptr, nullptr);
    }
  }
}

// Round 11
// 288.866 us; speedup vs baseline: 1.3202x; 1.0436x over previous
//
#include <hip/hip_runtime.h>

// LocalGraphTransformerEncoder on MI355X (gfx950). Round 17.
// R17 = revert to R13 exactly (best verified: 289.5us).
// R14-R16 post-mortem: epi+Wo K=1280 fusion + prep measured cost-neutral-
// to-negative (301.5us with prep tail fixed) -- redundant wide-A reads +
// 20 barrier rounds/block + prep work eat the saved dispatch. Locked out.
// Standing lessons:
//  - no persistent grid barriers (R8/R9: ~65us/barrier regardless of poll
//    style; suspect per-wave agent-scope fence L2 wb/inv).
//  - sim+exp must be edge-parallel across the grid (R11: 243us tail).
//  - accum serial edge chain per block <=32 (R12: 88us hub-row tail).
//  - never shrink a phase's parallel width to save a dispatch (R14/R15).
// Plateau diagnosis: ~17 dispatches, every kernel <42us, MfmaUtil~0,
// HBM<5% during our kernels -> launch-structure bound, not HW roofline.

#define MAXE  16384
#define NONX  22080
#define BF16_TOTAL 1441792

typedef __attribute__((ext_vector_type(8))) short bf16x8;
typedef __attribute__((ext_vector_type(4))) float f32x4;

struct PtrPack { const void* p[23]; };

__device__ __forceinline__ float bf2f(unsigned short s) {
  return __uint_as_float(((unsigned)s) << 16);
}
__device__ __forceinline__ unsigned short f2bf(float f) {
  unsigned u = __float_as_uint(f);
  u += 0x7fffu + ((u >> 16) & 1u);
  return (unsigned short)(u >> 16);
}
__device__ __forceinline__ float gelu_f(float x) {
  return 0.5f * x * (1.0f + erff(x * 0.70710678118654752440f));
}
__device__ __forceinline__ float wave_red_sum(float v) {
#pragma unroll
  for (int o = 32; o > 0; o >>= 1) v += __shfl_xor(v, o);
  return v;
}

__device__ __forceinline__ void edge_feats(int i, int j, float cxi, float cyi,
                                           float cxj, float cyj, float lsd, float* e) {
  float dx = cxj - cxi, dy = cyj - cyi;
  float dist = sqrtf(dx * dx + dy * dy + 1e-8f);
  e[0] = dx; e[1] = dy; e[2] = dist; e[3] = dist / lsd;
  bool qic = (i == 0), kic = (j == 0), eye = (i == j);
  e[4] = qic ? 1.f : 0.f;
  e[5] = kic ? 1.f : 0.f;
  e[6] = eye ? 1.f : 0.f;
  e[7] = (!qic && !kic && !eye) ? 1.f : 0.f;
  int hi = (i == 0) ? 0 : ((i < 128) ? 1 : 2);
  int hj = (j == 0) ? 0 : ((j < 128) ? 1 : 2);
  e[8] = (hi == hj) ? 1.f : 0.f;
  int hd = hj - hi;
  e[9] = (float)(hd < 0 ? -hd : hd);
}

// ---------- convert: fp32 smalls + bf16 weights + valid + rowsum zero ----------
__global__ __launch_bounds__(256) void k_convert(PtrPack pp, float* __restrict__ blobF,
                                                 unsigned short* __restrict__ blobB,
                                                 int* __restrict__ valid,
                                                 float* __restrict__ rowsum,
                                                 int* __restrict__ gctr) {
  bool isf32 = (*(const unsigned*)pp.p[15] == 0x3F800000u);
  int t = threadIdx.x;
  if (blockIdx.x == 0 && t == 0) *gctr = 0;
  if (blockIdx.x < 1024) {
    if (blockIdx.x < 32) rowsum[blockIdx.x * 256 + t] = 0.f;
    int r = blockIdx.x;
    int idx = r * 256 + t;
    float v = isf32 ? ((const float*)pp.p[0])[idx]
                    : bf2f(((const unsigned short*)pp.p[0])[idx]);
    blobF[idx] = v;
    __shared__ float s[4];
    float a = wave_red_sum(fabsf(v));
    if ((t & 63) == 0) s[t >> 6] = a;
    __syncthreads();
    if (t == 0) valid[r] = ((s[0] + s[1] + s[2] + s[3]) > 0.0f) || ((r & 255) == 0);
  } else {
    const int fst[16] = {0,2048,7680,8192,10240,10304,15936,16448,16960,17472,17984,18496,19008,19520,21568,22080};
    const int fsz[15] = {2048,5632,512,2048,8,5632,512,512,512,512,512,512,512,2048,512};
    const int fin[15] = {1,5,6,7,8,9,10,12,14,15,16,17,18,20,22};
    const int bst[8]  = {0,131072,262144,393216,524288,655360,1179648,1441792};
    const int bin[7]  = {2,3,4,13,11,19,21};
    const int NUNITS = NONX + BF16_TOTAL / 4;   // bf16 handled 4-at-a-time
    for (int u = (blockIdx.x - 1024) * 256 + t; u < NUNITS; u += 1024 * 256) {
      if (u < NONX) {
        int s = 0;
        while (s < 14 && u >= fst[s + 1]) ++s;
        int e = u - fst[s];
        float v = 0.f;
        if (e < fsz[s]) v = isf32 ? ((const float*)pp.p[fin[s]])[e]
                                  : bf2f(((const unsigned short*)pp.p[fin[s]])[e]);
        blobF[262144 + u] = v;
      } else {
        int bi = (u - NONX) * 4;       // quad of bf16 elems; sections 64-aligned
        int s = 0;
        while (s < 6 && bi >= bst[s + 1]) ++s;
        int e = bi - bst[s];
        ushort4 o;
        if (isf32) {
          const float* sp = (const float*)pp.p[bin[s]] + e;
          o.x = f2bf(sp[0]); o.y = f2bf(sp[1]); o.z = f2bf(sp[2]); o.w = f2bf(sp[3]);
        } else {
          o = *(const ushort4*)((const unsigned short*)pp.p[bin[s]] + e);
        }
        *(ushort4*)&blobB[bi] = o;
      }
    }
  }
}

// ---------- kNN: one wave per node; 3 rounds of packed-key argmin ----------
__global__ __launch_bounds__(256) void k_knn(const float* __restrict__ cf,
                                             const int* __restrict__ valid,
                                             int* __restrict__ knn) {
  int blk = blockIdx.x;
  int b = blk >> 6;
  int w = threadIdx.x >> 6, lane = threadIdx.x & 63;
  int i = (blk & 63) * 4 + w;
  const float2* cc = (const float2*)(cf + b * 512);
  float2 ci = cc[i];
  bool vi = (valid[b * 256 + i] != 0) && (i != 0);
  unsigned long long key[4];
#pragma unroll
  for (int k = 0; k < 4; ++k) {
    int j = lane + 64 * k;
    bool ok = vi && (j != 0) && (j != i) && (valid[b * 256 + j] != 0);
    unsigned long long kk = ~0ull;
    if (ok) {
      float2 cj = cc[j];
      float dx = ci.x - cj.x, dy = ci.y - cj.y;
      float dd = sqrtf(dx * dx + dy * dy);
      kk = (((unsigned long long)__float_as_uint(dd)) << 32) | (unsigned)j;
    }
    key[k] = kk;
  }
  int out[3];
#pragma unroll
  for (int rnd = 0; rnd < 3; ++rnd) {
    unsigned long long m = key[0];
    if (key[1] < m) m = key[1];
    if (key[2] < m) m = key[2];
    if (key[3] < m) m = key[3];
#pragma unroll
    for (int o = 32; o > 0; o >>= 1) {
      unsigned long long om = __shfl_xor(m, o);
      if (om < m) m = om;
    }
    out[rnd] = (m != ~0ull) ? (int)(m & 0xFFFFFFFFull) : -1;
#pragma unroll
    for (int k = 0; k < 4; ++k)
      if (key[k] == m) key[k] = ~0ull;
  }
  if (lane == 0) {
    knn[(b * 256 + i) * 3 + 0] = out[0];
    knn[(b * 256 + i) * 3 + 1] = out[1];
    knn[(b * 256 + i) * 3 + 2] = out[2];
  }
}

// ---------- CSR build (shuffle scan) ----------
__global__ __launch_bounds__(256) void k_csr(const float* __restrict__ cf,
                                             const int* __restrict__ valid,
                                             const int* __restrict__ knn,
                                             float* __restrict__ lsbuf,
                                             int* __restrict__ deg, int* __restrict__ rowptr,
                                             int* __restrict__ rowof, int* __restrict__ colsb,
                                             int* __restrict__ gctr) {
  int b = blockIdx.x, t = threadIdx.x;
  __shared__ unsigned adjw[256][8];
  __shared__ float sred[8];
  __shared__ int wsum[4];
  __shared__ int sbase;

  int r = b * 256 + t;
  float cx = cf[r * 2 + 0], cy = cf[r * 2 + 1];
  int lv = valid[r];
#pragma unroll
  for (int w = 0; w < 8; ++w) adjw[t][w] = 0u;
  __syncthreads();

  atomicOr(&adjw[t][t >> 5], 1u << (t & 31));
  if (t >= 1 && lv) {
    atomicOr(&adjw[0][t >> 5], 1u << (t & 31));
    atomicOr(&adjw[t][0], 1u);
  }
#pragma unroll
  for (int s = 0; s < 3; ++s) {
    int j = knn[r * 3 + s];
    if (j >= 0) {
      atomicOr(&adjw[t][j >> 5], 1u << (j & 31));
      atomicOr(&adjw[j][t >> 5], 1u << (t & 31));
    }
  }
  float cdist = sqrtf(cx * cx + cy * cy + 1e-8f);
  int nvm = (t >= 1) && lv;
  float rs = wave_red_sum(nvm ? cdist : 0.0f);
  float rc = wave_red_sum(nvm ? 1.0f : 0.0f);
  if ((t & 63) == 0) { sred[t >> 6] = rs; sred[4 + (t >> 6)] = rc; }
  __syncthreads();

  if (t == 0) {
    float totd = sred[0] + sred[1] + sred[2] + sred[3];
    float totc = sred[4] + sred[5] + sred[6] + sred[7];
    float ls = totd / fmaxf(totc, 1.0f);
    ls = (ls > 0.0f) ? ls : 1.0f;
    lsbuf[b] = fmaxf(ls, 1e-6f);
  }

  int dg = 0;
#pragma unroll
  for (int w = 0; w < 8; ++w) dg += __popc(adjw[t][w]);

  int lane = t & 63, wv = t >> 6;
  int x = dg;
#pragma unroll
  for (int off = 1; off < 64; off <<= 1) {
    int y = __shfl_up(x, off);
    if (lane >= off) x += y;
  }
  if (lane == 63) wsum[wv] = x;
  __syncthreads();
  if (t == 0) sbase = atomicAdd(gctr, wsum[0] + wsum[1] + wsum[2] + wsum[3]);
  __syncthreads();
  int woff = 0;
#pragma unroll
  for (int k2i = 0; k2i < 4; ++k2i) woff += (k2i < wv) ? wsum[k2i] : 0;
  int off0 = sbase + woff + x - dg;

  rowptr[r] = off0;
  deg[r] = dg;
  int o = off0;
#pragma unroll
  for (int w = 0; w < 8; ++w) {
    unsigned bits = adjw[t][w];
    while (bits) {
      int bp = __ffs(bits) - 1;
      colsb[o] = w * 32 + bp;
      rowof[o] = r;
      ++o;
      bits &= bits - 1;
    }
  }
}

// ---------- bf16 MFMA GEMM body: 16x64 tile, BK=64, full-K reg prefetch ----
// AMODE: 0=bf16 A | 1=gated fp32 (gate +512, lda=1024) | 2=plain fp32 | 3=LN-fused fp32
// OMODE: 0=fp32 | 1=probe bf16/fp32 | 2=bf16
// K must be a multiple of 256. AMODE 3 requires K==256.
template <int AMODE, int OMODE>
__device__ __forceinline__ void mfma_body(const void* Aptr, int lda,
                                          const unsigned short* __restrict__ B, int ldb, int n0B,
                                          const float* __restrict__ bias,
                                          const float* resid,
                                          void* C, int ldc, int n0C,
                                          int m0, int K, bool obf,
                                          const float* __restrict__ lnG,
                                          const float* __restrict__ lnB) {
  __shared__ short As[16][72];
  __shared__ short Bs[64][72];
  __shared__ float sG[256], sB2[256];
  int t = threadIdx.x, lane = t & 63, w = t >> 6;

  int am = t >> 3, ak = (t & 7) * 8;   // A staging (t < 128): 16 rows x 64 k
  int bk = t >> 2, bn = (t & 3) * 16;  // B staging (all): 64 k x 64 n

  f32x4 acc;
  acc[0] = 0.f; acc[1] = 0.f; acc[2] = 0.f; acc[3] = 0.f;

  for (int kc = 0; kc < K; kc += 256) {
    // ---- prefetch 4 rounds of A and B into registers (independent loads) ----
    bf16x8 aB[4];
    float4 aF[4][2];
    float4 gF[4][2];
    bf16x8 bR[4][2];
#pragma unroll
    for (int r = 0; r < 4; ++r) {
      int k0 = kc + r * 64;
      if (t < 128) {
        if (AMODE == 0) {
          aB[r] = *(const bf16x8*)((const unsigned short*)Aptr +
                                   (size_t)(m0 + am) * lda + k0 + ak);
        } else {
          const float* ap = (const float*)Aptr + (size_t)(m0 + am) * lda + k0 + ak;
          aF[r][0] = *(const float4*)ap;
          aF[r][1] = *(const float4*)(ap + 4);
          if (AMODE == 1) {
            gF[r][0] = *(const float4*)(ap + 512);
            gF[r][1] = *(const float4*)(ap + 516);
          }
        }
      }
      const unsigned short* bp = B + (size_t)(k0 + bk) * ldb + n0B + bn;
      bR[r][0] = *(const bf16x8*)bp;
      bR[r][1] = *(const bf16x8*)(bp + 8);
    }

    // ---- AMODE 3: LN gamma/beta to LDS; row stats from prefetched regs ----
    float mm = 0.f, rstd = 0.f;
    if (AMODE == 3) {
      sG[t] = lnG[t]; sB2[t] = lnB[t];
      if (t < 128) {
        float s = 0.f, ss = 0.f;
#pragma unroll
        for (int r = 0; r < 4; ++r)
#pragma unroll
          for (int h2 = 0; h2 < 2; ++h2) {
            float4 v4 = aF[r][h2];
            s += v4.x + v4.y + v4.z + v4.w;
            ss += v4.x * v4.x + v4.y * v4.y + v4.z * v4.z + v4.w * v4.w;
          }
        s += __shfl_xor(s, 1); s += __shfl_xor(s, 2); s += __shfl_xor(s, 4);
        ss += __shfl_xor(ss, 1); ss += __shfl_xor(ss, 2); ss += __shfl_xor(ss, 4);
        mm = s * (1.f / 256.f);
        float var = ss * (1.f / 256.f) - mm * mm;
        rstd = 1.f / sqrtf(var + 1e-5f);
      }
      __syncthreads();
    }

    // ---- 4 rounds: stage from registers, MFMA ----
#pragma unroll
    for (int r = 0; r < 4; ++r) {
      if (t < 128) {
        if (AMODE == 0) {
          *(bf16x8*)&As[am][ak] = aB[r];
        } else if (AMODE == 1) {
          float4 a0 = aF[r][0], a1 = aF[r][1];
          float4 g0 = gF[r][0], g1 = gF[r][1];
          short tmp[8];
          tmp[0] = (short)f2bf(a0.x * gelu_f(g0.x));
          tmp[1] = (short)f2bf(a0.y * gelu_f(g0.y));
          tmp[2] = (short)f2bf(a0.z * gelu_f(g0.z));
          tmp[3] = (short)f2bf(a0.w * gelu_f(g0.w));
          tmp[4] = (short)f2bf(a1.x * gelu_f(g1.x));
          tmp[5] = (short)f2bf(a1.y * gelu_f(g1.y));
          tmp[6] = (short)f2bf(a1.z * gelu_f(g1.z));
          tmp[7] = (short)f2bf(a1.w * gelu_f(g1.w));
          *(bf16x8*)&As[am][ak] = *(bf16x8*)tmp;
        } else if (AMODE == 2) {
          float4 a0 = aF[r][0], a1 = aF[r][1];
          short tmp[8];
          tmp[0] = (short)f2bf(a0.x); tmp[1] = (short)f2bf(a0.y);
          tmp[2] = (short)f2bf(a0.z); tmp[3] = (short)f2bf(a0.w);
          tmp[4] = (short)f2bf(a1.x); tmp[5] = (short)f2bf(a1.y);
          tmp[6] = (short)f2bf(a1.z); tmp[7] = (short)f2bf(a1.w);
          *(bf16x8*)&As[am][ak] = *(bf16x8*)tmp;
        } else {
          float4 a0 = aF[r][0], a1 = aF[r][1];
          int kb = kc + r * 64 + ak;
          short tmp[8];
          tmp[0] = (short)f2bf((a0.x - mm) * rstd * sG[kb + 0] + sB2[kb + 0]);
          tmp[1] = (short)f2bf((a0.y - mm) * rstd * sG[kb + 1] + sB2[kb + 1]);
          tmp[2] = (short)f2bf((a0.z - mm) * rstd * sG[kb + 2] + sB2[kb + 2]);
          tmp[3] = (short)f2bf((a0.w - mm) * rstd * sG[kb + 3] + sB2[kb + 3]);
          tmp[4] = (short)f2bf((a1.x - mm) * rstd * sG[kb + 4] + sB2[kb + 4]);
          tmp[5] = (short)f2bf((a1.y - mm) * rstd * sG[kb + 5] + sB2[kb + 5]);
          tmp[6] = (short)f2bf((a1.z - mm) * rstd * sG[kb + 6] + sB2[kb + 6]);
          tmp[7] = (short)f2bf((a1.w - mm) * rstd * sG[kb + 7] + sB2[kb + 7]);
          *(bf16x8*)&As[am][ak] = *(bf16x8*)tmp;
        }
      }
      {
        bf16x8 bv0 = bR[r][0], bv1 = bR[r][1];
#pragma unroll
        for (int i2 = 0; i2 < 8; ++i2) Bs[bn + i2][bk] = bv0[i2];
#pragma unroll
        for (int i2 = 0; i2 < 8; ++i2) Bs[bn + 8 + i2][bk] = bv1[i2];
      }
      __syncthreads();
      int q = lane >> 4;
      bf16x8 af0 = *(const bf16x8*)&As[lane & 15][q * 8];
      bf16x8 af1 = *(const bf16x8*)&As[lane & 15][32 + q * 8];
      bf16x8 bf0 = *(const bf16x8*)&Bs[w * 16 + (lane & 15)][q * 8];
      bf16x8 bf1 = *(const bf16x8*)&Bs[w * 16 + (lane & 15)][32 + q * 8];
      acc = __builtin_amdgcn_mfma_f32_16x16x32_bf16(af0, bf0, acc, 0, 0, 0);
      acc = __builtin_amdgcn_mfma_f32_16x16x32_bf16(af1, bf1, acc, 0, 0, 0);
      __syncthreads();
    }
  }

  int q = lane >> 4;
  int cn = w * 16 + (lane & 15);
  int col = n0C + cn;
  float bv = bias ? bias[n0B + cn] : 0.0f;
#pragma unroll
  for (int rr = 0; rr < 4; ++rr) {
    int row = m0 + q * 4 + rr;
    float v = acc[rr] + bv;
    if (resid) v += resid[(size_t)row * ldc + col];
    if (OMODE == 2 || (OMODE == 1 && obf)) {
      ((unsigned short*)C)[(size_t)row * ldc + col] = f2bf(v);
    } else {
      ((float*)C)[(size_t)row * ldc + col] = v;
    }
  }
}

template <int AMODE, int OMODE>
__global__ __launch_bounds__(256) void k_mfma(const void* A, int lda, int aYoffBytes,
                                              const unsigned short* B, int ldb,
                                              const float* bias, const float* resid,
                                              void* C, int ldc, int K,
                                              const unsigned* probe,
                                              const float* lnG, const float* lnB) {
  bool obf = (OMODE == 1) && probe && (*probe != 0x3F800000u);
  int n0 = blockIdx.y * 64;
  const void* Ap = (const char*)A + (size_t)aYoffBytes * blockIdx.y;
  mfma_body<AMODE, OMODE>(Ap, lda, B, ldb, n0, bias, resid, C, ldc, n0,
                          blockIdx.x * 16, K, obf, lnG, lnB);
}

// QKV with fused LN: Wq/Wk/Wv sections are 131072 elems apart in the bf16 blob.
__global__ __launch_bounds__(256) void k_mfma_qkv(const float* X,
                                                  const float* lnG, const float* lnB,
                                                  const unsigned short* WqL, float* qkv) {
  int sel = blockIdx.y >> 2;
  const unsigned short* B = WqL + sel * 131072;
  int n0B = (blockIdx.y & 3) * 64;
  int n0C = blockIdx.y * 64;
  mfma_body<3, 0>(X, 256, B, 256, n0B, nullptr, nullptr, qkv, 768, n0C,
                  blockIdx.x * 16, 256, false, lnG, lnB);
}

// ---------- simz: sim + exp + rowsum atomics (edge-parallel) ----------
// Blocks 0..3 additionally zero the hub rows' tb/vs slots (r = bx*256).
__global__ __launch_bounds__(256) void k_simz(const float* __restrict__ cf,
                                              const float* __restrict__ qkv,
                                              const int* __restrict__ rowof,
                                              const int* __restrict__ colsb,
                                              const int* __restrict__ gctr,
                                              const float* __restrict__ lsbuf,
                                              const float* __restrict__ ebW1,
                                              const float* __restrict__ ebB1,
                                              const float* __restrict__ ebW2,
                                              const float* __restrict__ ebB2,
                                              float* __restrict__ esim,
                                              float* __restrict__ rowsum,
                                              float* __restrict__ tb,
                                              float* __restrict__ vs) {
  int t = threadIdx.x;
  if (blockIdx.x < 4) {
    int hr = blockIdx.x * 256;
    size_t tz = (size_t)hr * 1024 + t;
    tb[tz] = 0.f; tb[tz + 256] = 0.f; tb[tz + 512] = 0.f; tb[tz + 768] = 0.f;
    vs[(size_t)hr * 256 + t] = 0.f;
  }
  int E = *gctr;
  int lane = t & 63, w = t >> 6;
  float W1r[4][10], B1r[4], W2r[4][4];
#pragma unroll
  for (int kk = 0; kk < 4; ++kk) {
    int c = kk * 64 + lane;
    B1r[kk] = ebB1[c];
#pragma unroll
    for (int f = 0; f < 10; ++f) W1r[kk][f] = ebW1[f * 256 + c];
    float4 w2 = *(const float4*)(ebW2 + c * 4);
    W2r[kk][0] = w2.x; W2r[kk][1] = w2.y; W2r[kk][2] = w2.z; W2r[kk][3] = w2.w;
  }
  float b20 = ebB2[0], b21 = ebB2[1], b22 = ebB2[2], b23 = ebB2[3];
  for (int g = blockIdx.x * 4 + w; g < E; g += 4096) {
    int r = rowof[g], j = colsb[g];
    int b = r >> 8, i = r & 255;
    float ls = lsbuf[b];
    const float2* cc = (const float2*)cf;
    float2 ci = cc[b * 256 + i], cj = cc[b * 256 + j];
    float ef[10];
    edge_feats(i, j, ci.x, ci.y, cj.x, cj.y, ls, ef);
    float red[8];
#pragma unroll
    for (int z = 0; z < 8; ++z) red[z] = 0.0f;
#pragma unroll
    for (int kk = 0; kk < 4; ++kk) {
      int c = kk * 64 + lane;
      float h1 = B1r[kk];
#pragma unroll
      for (int f = 0; f < 10; ++f) h1 += ef[f] * W1r[kk][f];
      float g1 = gelu_f(h1);
      red[4] += g1 * W2r[kk][0];
      red[5] += g1 * W2r[kk][1];
      red[6] += g1 * W2r[kk][2];
      red[7] += g1 * W2r[kk][3];
      red[kk] = qkv[(size_t)r * 768 + c] * qkv[((size_t)(b * 256 + j)) * 768 + 256 + c];
    }
#pragma unroll
    for (int z = 0; z < 8; ++z) {
#pragma unroll
      for (int o = 32; o > 0; o >>= 1) red[z] += __shfl_xor(red[z], o);
    }
    if (lane == 0) {
      float e0 = expf(red[0] * 0.125f + red[4] + b20);
      float e1 = expf(red[1] * 0.125f + red[5] + b21);
      float e2 = expf(red[2] * 0.125f + red[6] + b22);
      float e3 = expf(red[3] * 0.125f + red[7] + b23);
      *(float4*)&esim[(size_t)g * 4] = make_float4(e0, e1, e2, e3);
      atomicAdd(&rowsum[r * 4 + 0], e0);
      atomicAdd(&rowsum[r * 4 + 1], e1);
      atomicAdd(&rowsum[r * 4 + 2], e2);
      atomicAdd(&rowsum[r * 4 + 3], e3);
    }
  }
}

// ---------- accum: hybrid chunked (32-edge chunks) ----------
// grid = 1052: x<1024 -> (row x, chunk 0); x>=1024 -> hub rows' chunks 1..7.
// Whole-row chunks (d<=32) store directly; hub chunks atomicAdd (slots
// pre-zeroed by k_simz).
__global__ __launch_bounds__(256, 8) void k_accum(const float* __restrict__ cf,
                                                  const float* __restrict__ qkv,
                                                  const int* __restrict__ rowptr,
                                                  const int* __restrict__ deg,
                                                  const int* __restrict__ colsb,
                                                  const float* __restrict__ esim,
                                                  const float* __restrict__ rowsum,
                                                  const float* __restrict__ lsbuf,
                                                  const float* __restrict__ evW1,
                                                  const float* __restrict__ evB1,
                                                  float* __restrict__ tb,
                                                  float* __restrict__ vs) {
  int x = blockIdx.x;
  int r, ch;
  if (x < 1024) { r = x; ch = 0; }
  else { int i5 = x - 1024; r = (i5 / 7) * 256; ch = 1 + i5 % 7; }
  int d = deg[r];
  int e0 = ch * 32;
  if (e0 >= d) return;
  int n = min(32, d - e0);
  bool whole = (ch == 0) && (d <= 32);
  int base = rowptr[r] + e0;
  int b = r >> 8, i = r & 255;
  int u = threadIdx.x, h = u >> 6;

  __shared__ int scols[32];
  __shared__ float4 sattn[32];
  __shared__ float sef[32][10];
  if (u < n) {
    float4 S4 = *(const float4*)&rowsum[r * 4];
    int j = colsb[base + u];
    scols[u] = j;
    float4 e = *(const float4*)&esim[(size_t)(base + u) * 4];
    sattn[u] = make_float4(e.x / S4.x, e.y / S4.y, e.z / S4.z, e.w / S4.w);
    float ls = lsbuf[b];
    const float2* cc = (const float2*)cf;
    float2 ci = cc[b * 256 + i], cj = cc[b * 256 + j];
    float ef[10];
    edge_feats(i, j, ci.x, ci.y, cj.x, cj.y, ls, ef);
#pragma unroll
    for (int f = 0; f < 10; ++f) sef[u][f] = ef[f];
  }
  __syncthreads();

  float evb = evB1[u];
  float w1r[10];
#pragma unroll
  for (int f = 0; f < 10; ++f) w1r[f] = evW1[f * 256 + u];
  float t0 = 0.f, t1 = 0.f, t2 = 0.f, t3 = 0.f, va = 0.f;
#pragma unroll 4
  for (int e = 0; e < n; ++e) {
    float4 a = sattn[e];
    int j = scols[e];
    float h1 = evb;
#pragma unroll
    for (int f = 0; f < 10; ++f) h1 += sef[e][f] * w1r[f];
    float g1 = gelu_f(h1);
    t0 += a.x * g1; t1 += a.y * g1; t2 += a.z * g1; t3 += a.w * g1;
    float ah = (h == 0) ? a.x : (h == 1) ? a.y : (h == 2) ? a.z : a.w;
    va += ah * qkv[((size_t)(b * 256 + j)) * 768 + 512 + u];
  }
  size_t tbase = (size_t)r * 1024 + u;
  if (whole) {
    tb[tbase]       = t0;
    tb[tbase + 256] = t1;
    tb[tbase + 512] = t2;
    tb[tbase + 768] = t3;
    vs[(size_t)r * 256 + u] = va;
  } else {
    atomicAdd(&tb[tbase], t0);
    atomicAdd(&tb[tbase + 256], t1);
    atomicAdd(&tb[tbase + 512], t2);
    atomicAdd(&tb[tbase + 768], t3);
    atomicAdd(&vs[(size_t)r * 256 + u], va);
  }
}

extern "C" void kernel_launch(void* const* d_in, const int* in_sizes, int n_in,
                              void* d_out, int out_size, void* d_ws, size_t ws_size,
                              hipStream_t stream) {
  (void)in_sizes; (void)n_in; (void)out_size; (void)ws_size;

  char* wp = (char*)d_ws;
  auto carve = [&](size_t bytes) -> char* {
    char* p = wp;
    wp += ((bytes + 255) / 256) * 256;
    return p;
  };
  int*   gctr   = (int*)carve(4);
  float* lsb    = (float*)carve(16);
  int*   valid  = (int*)carve(1024 * 4);
  int*   deg    = (int*)carve(1024 * 4);
  int*   rowptr = (int*)carve(1024 * 4);
  int*   rowof  = (int*)carve(MAXE * 4);
  int*   colsb  = (int*)carve(MAXE * 4);
  int*   knn    = (int*)carve(1024 * 3 * 4);
  float* rowsum = (float*)carve(8192 * 4);
  float* sim    = (float*)carve((size_t)MAXE * 16);
  float* blobF  = (float*)carve((size_t)(262144 + NONX) * 4);
  unsigned short* blobB = (unsigned short*)carve((size_t)BF16_TOTAL * 2);
  float* qkv    = (float*)carve((size_t)1024 * 768 * 4);
  float* xcur   = (float*)carve((size_t)262144 * 4);
  float* tb     = (float*)carve((size_t)1048576 * 4);   // t-accum; reused as FF hidden
  float* vs     = (float*)carve((size_t)262144 * 4);
  unsigned short* oi = (unsigned short*)carve((size_t)262144 * 2);

  // fp32 blob pointers
  const float* Xf    = blobF + 0;
  const float* Cf    = blobF + 262144;
  const float* ebW1  = blobF + 264192;
  const float* ebB1  = blobF + 269824;
  const float* ebW2  = blobF + 270336;
  const float* ebB2  = blobF + 272384;
  const float* evW1  = blobF + 272448;
  const float* evB1  = blobF + 278080;
  const float* evB2  = blobF + 278592;
  const float* boB   = blobF + 279104;
  const float* ln1w  = blobF + 279616;
  const float* ln1b  = blobF + 280128;
  const float* ln2w  = blobF + 280640;
  const float* ln2b  = blobF + 281152;
  const float* ffb1  = blobF + 281664;
  const float* ffb2  = blobF + 283712;
  // bf16 blob pointers
  const unsigned short* WqB   = blobB + 0;
  const unsigned short* WoB   = blobB + 393216;
  const unsigned short* evW2B = blobB + 524288;
  const unsigned short* ffw1B = blobB + 655360;
  const unsigned short* ffw2B = blobB + 1179648;

  PtrPack pp;
  for (int i = 0; i < 23; ++i) pp.p[i] = d_in[i];
  const unsigned* probe = (const unsigned*)d_in[15];

  k_convert<<<2048, 256, 0, stream>>>(pp, blobF, blobB, valid, rowsum, gctr);
  k_knn<<<256, 256, 0, stream>>>(Cf, valid, knn);
  k_csr<<<4, 256, 0, stream>>>(Cf, valid, knn, lsb, deg, rowptr, rowof, colsb, gctr);

  for (int l = 0; l < 2; ++l) {
    const float* xsrc = (l == 0) ? Xf : xcur;
    float* rsumL = rowsum + l * 4096;
    k_mfma_qkv<<<dim3(64, 12), 256, 0, stream>>>(xsrc, ln1w + l * 256, ln1b + l * 256,
                                                 WqB + l * 65536, qkv);
    k_simz<<<1024, 256, 0, stream>>>(Cf, qkv, rowof, colsb, gctr, lsb,
                                     ebW1 + l * 2816, ebB1 + l * 256,
                                     ebW2 + l * 1024, ebB2 + l * 4,
                                     sim, rsumL, tb, vs);
    k_accum<<<1052, 256, 0, stream>>>(Cf, qkv, rowptr, deg, colsb, sim, rsumL, lsb,
                                      evW1 + l * 2816, evB1 + l * 256, tb, vs);
    // epi GEMM: oi = vs + t_head @ evW2 + evB2   (A offset 256 floats per y-block)
    k_mfma<2, 2><<<dim3(64, 4), 256, 0, stream>>>(tb, 1024, 1024, evW2B + l * 65536, 256,
                                                  evB2 + l * 256, vs, oi, 256, 256,
                                                  nullptr, nullptr, nullptr);
    // Wo GEMM + residual
    k_mfma<0, 0><<<dim3(64, 4), 256, 0, stream>>>(oi, 256, 0, WoB + l * 65536, 256,
                                                  boB + l * 256, xsrc, xcur, 256, 256,
                                                  nullptr, nullptr, nullptr);
    // FF1 with fused LN2
    k_mfma<3, 0><<<dim3(64, 16), 256, 0, stream>>>(xcur, 256, 0, ffw1B + l * 262144, 1024,
                                                   ffb1 + l * 1024, nullptr, tb, 1024, 256,
                                                   nullptr, ln2w + l * 256, ln2b + l * 256);
    // FF2 gated + residual
    if (l == 0) {
      k_mfma<1, 0><<<dim3(64, 4), 256, 0, stream>>>(tb, 1024, 0, ffw2B + l * 131072, 256,
                                                    ffb2 + l * 256, xcur, xcur, 256, 512,
                                                    nullptr, nullptr, nullptr);
    } else {
      k_mfma<1, 1><<<dim3(64, 4), 256, 0, stream>>>(tb, 1024, 0, ffw2B + l * 131072, 256,
                                                    ffb2 + l * 256, xcur, d_out, 256, 512,
                                                    probe, nullptr, nullptr);
    }
  }
}

// Round 12
// 284.395 us; speedup vs baseline: 1.3409x; 1.0157x over previous
//
#include <hip/hip_runtime.h>

// LocalGraphTransformerEncoder on MI355X (gfx950). Round 18.
// R17 (=R13) reconfirmed 288.9us. R18: LDS double-buffer in mfma_body --
// rounds go {stage buf[r&1]; sync; MFMA} (1 barrier/round, was 2): data is
// already register-prefetched, so alternating buffers removes the trailing
// sync. Cross-round/chunk safety: wave's round-r LDS reads complete before
// it reaches round r+1's collective barrier; buffer reuse is 2 rounds away.
// LDS ~25KB/block (no occupancy impact). Only the GEMM template changes.
// Standing lessons: no persistent grid barriers (R8/R9 ~65us each);
// sim edge-parallel (R11); accum chunk <=32 (R12); never shrink parallel
// width to save a dispatch (R14/R15); epi+Wo K=1280 fusion is cost-negative
// (R14-R16, locked out).

#define MAXE  16384
#define NONX  22080
#define BF16_TOTAL 1441792

typedef __attribute__((ext_vector_type(8))) short bf16x8;
typedef __attribute__((ext_vector_type(4))) float f32x4;

struct PtrPack { const void* p[23]; };

__device__ __forceinline__ float bf2f(unsigned short s) {
  return __uint_as_float(((unsigned)s) << 16);
}
__device__ __forceinline__ unsigned short f2bf(float f) {
  unsigned u = __float_as_uint(f);
  u += 0x7fffu + ((u >> 16) & 1u);
  return (unsigned short)(u >> 16);
}
__device__ __forceinline__ float gelu_f(float x) {
  return 0.5f * x * (1.0f + erff(x * 0.70710678118654752440f));
}
__device__ __forceinline__ float wave_red_sum(float v) {
#pragma unroll
  for (int o = 32; o > 0; o >>= 1) v += __shfl_xor(v, o);
  return v;
}

__device__ __forceinline__ void edge_feats(int i, int j, float cxi, float cyi,
                                           float cxj, float cyj, float lsd, float* e) {
  float dx = cxj - cxi, dy = cyj - cyi;
  float dist = sqrtf(dx * dx + dy * dy + 1e-8f);
  e[0] = dx; e[1] = dy; e[2] = dist; e[3] = dist / lsd;
  bool qic = (i == 0), kic = (j == 0), eye = (i == j);
  e[4] = qic ? 1.f : 0.f;
  e[5] = kic ? 1.f : 0.f;
  e[6] = eye ? 1.f : 0.f;
  e[7] = (!qic && !kic && !eye) ? 1.f : 0.f;
  int hi = (i == 0) ? 0 : ((i < 128) ? 1 : 2);
  int hj = (j == 0) ? 0 : ((j < 128) ? 1 : 2);
  e[8] = (hi == hj) ? 1.f : 0.f;
  int hd = hj - hi;
  e[9] = (float)(hd < 0 ? -hd : hd);
}

// ---------- convert: fp32 smalls + bf16 weights + valid + rowsum zero ----------
__global__ __launch_bounds__(256) void k_convert(PtrPack pp, float* __restrict__ blobF,
                                                 unsigned short* __restrict__ blobB,
                                                 int* __restrict__ valid,
                                                 float* __restrict__ rowsum,
                                                 int* __restrict__ gctr) {
  bool isf32 = (*(const unsigned*)pp.p[15] == 0x3F800000u);
  int t = threadIdx.x;
  if (blockIdx.x == 0 && t == 0) *gctr = 0;
  if (blockIdx.x < 1024) {
    if (blockIdx.x < 32) rowsum[blockIdx.x * 256 + t] = 0.f;
    int r = blockIdx.x;
    int idx = r * 256 + t;
    float v = isf32 ? ((const float*)pp.p[0])[idx]
                    : bf2f(((const unsigned short*)pp.p[0])[idx]);
    blobF[idx] = v;
    __shared__ float s[4];
    float a = wave_red_sum(fabsf(v));
    if ((t & 63) == 0) s[t >> 6] = a;
    __syncthreads();
    if (t == 0) valid[r] = ((s[0] + s[1] + s[2] + s[3]) > 0.0f) || ((r & 255) == 0);
  } else {
    const int fst[16] = {0,2048,7680,8192,10240,10304,15936,16448,16960,17472,17984,18496,19008,19520,21568,22080};
    const int fsz[15] = {2048,5632,512,2048,8,5632,512,512,512,512,512,512,512,2048,512};
    const int fin[15] = {1,5,6,7,8,9,10,12,14,15,16,17,18,20,22};
    const int bst[8]  = {0,131072,262144,393216,524288,655360,1179648,1441792};
    const int bin[7]  = {2,3,4,13,11,19,21};
    const int NUNITS = NONX + BF16_TOTAL / 4;   // bf16 handled 4-at-a-time
    for (int u = (blockIdx.x - 1024) * 256 + t; u < NUNITS; u += 1024 * 256) {
      if (u < NONX) {
        int s = 0;
        while (s < 14 && u >= fst[s + 1]) ++s;
        int e = u - fst[s];
        float v = 0.f;
        if (e < fsz[s]) v = isf32 ? ((const float*)pp.p[fin[s]])[e]
                                  : bf2f(((const unsigned short*)pp.p[fin[s]])[e]);
        blobF[262144 + u] = v;
      } else {
        int bi = (u - NONX) * 4;       // quad of bf16 elems; sections 64-aligned
        int s = 0;
        while (s < 6 && bi >= bst[s + 1]) ++s;
        int e = bi - bst[s];
        ushort4 o;
        if (isf32) {
          const float* sp = (const float*)pp.p[bin[s]] + e;
          o.x = f2bf(sp[0]); o.y = f2bf(sp[1]); o.z = f2bf(sp[2]); o.w = f2bf(sp[3]);
        } else {
          o = *(const ushort4*)((const unsigned short*)pp.p[bin[s]] + e);
        }
        *(ushort4*)&blobB[bi] = o;
      }
    }
  }
}

// ---------- kNN: one wave per node; 3 rounds of packed-key argmin ----------
__global__ __launch_bounds__(256) void k_knn(const float* __restrict__ cf,
                                             const int* __restrict__ valid,
                                             int* __restrict__ knn) {
  int blk = blockIdx.x;
  int b = blk >> 6;
  int w = threadIdx.x >> 6, lane = threadIdx.x & 63;
  int i = (blk & 63) * 4 + w;
  const float2* cc = (const float2*)(cf + b * 512);
  float2 ci = cc[i];
  bool vi = (valid[b * 256 + i] != 0) && (i != 0);
  unsigned long long key[4];
#pragma unroll
  for (int k = 0; k < 4; ++k) {
    int j = lane + 64 * k;
    bool ok = vi && (j != 0) && (j != i) && (valid[b * 256 + j] != 0);
    unsigned long long kk = ~0ull;
    if (ok) {
      float2 cj = cc[j];
      float dx = ci.x - cj.x, dy = ci.y - cj.y;
      float dd = sqrtf(dx * dx + dy * dy);
      kk = (((unsigned long long)__float_as_uint(dd)) << 32) | (unsigned)j;
    }
    key[k] = kk;
  }
  int out[3];
#pragma unroll
  for (int rnd = 0; rnd < 3; ++rnd) {
    unsigned long long m = key[0];
    if (key[1] < m) m = key[1];
    if (key[2] < m) m = key[2];
    if (key[3] < m) m = key[3];
#pragma unroll
    for (int o = 32; o > 0; o >>= 1) {
      unsigned long long om = __shfl_xor(m, o);
      if (om < m) m = om;
    }
    out[rnd] = (m != ~0ull) ? (int)(m & 0xFFFFFFFFull) : -1;
#pragma unroll
    for (int k = 0; k < 4; ++k)
      if (key[k] == m) key[k] = ~0ull;
  }
  if (lane == 0) {
    knn[(b * 256 + i) * 3 + 0] = out[0];
    knn[(b * 256 + i) * 3 + 1] = out[1];
    knn[(b * 256 + i) * 3 + 2] = out[2];
  }
}

// ---------- CSR build (shuffle scan) ----------
__global__ __launch_bounds__(256) void k_csr(const float* __restrict__ cf,
                                             const int* __restrict__ valid,
                                             const int* __restrict__ knn,
                                             float* __restrict__ lsbuf,
                                             int* __restrict__ deg, int* __restrict__ rowptr,
                                             int* __restrict__ rowof, int* __restrict__ colsb,
                                             int* __restrict__ gctr) {
  int b = blockIdx.x, t = threadIdx.x;
  __shared__ unsigned adjw[256][8];
  __shared__ float sred[8];
  __shared__ int wsum[4];
  __shared__ int sbase;

  int r = b * 256 + t;
  float cx = cf[r * 2 + 0], cy = cf[r * 2 + 1];
  int lv = valid[r];
#pragma unroll
  for (int w = 0; w < 8; ++w) adjw[t][w] = 0u;
  __syncthreads();

  atomicOr(&adjw[t][t >> 5], 1u << (t & 31));
  if (t >= 1 && lv) {
    atomicOr(&adjw[0][t >> 5], 1u << (t & 31));
    atomicOr(&adjw[t][0], 1u);
  }
#pragma unroll
  for (int s = 0; s < 3; ++s) {
    int j = knn[r * 3 + s];
    if (j >= 0) {
      atomicOr(&adjw[t][j >> 5], 1u << (j & 31));
      atomicOr(&adjw[j][t >> 5], 1u << (t & 31));
    }
  }
  float cdist = sqrtf(cx * cx + cy * cy + 1e-8f);
  int nvm = (t >= 1) && lv;
  float rs = wave_red_sum(nvm ? cdist : 0.0f);
  float rc = wave_red_sum(nvm ? 1.0f : 0.0f);
  if ((t & 63) == 0) { sred[t >> 6] = rs; sred[4 + (t >> 6)] = rc; }
  __syncthreads();

  if (t == 0) {
    float totd = sred[0] + sred[1] + sred[2] + sred[3];
    float totc = sred[4] + sred[5] + sred[6] + sred[7];
    float ls = totd / fmaxf(totc, 1.0f);
    ls = (ls > 0.0f) ? ls : 1.0f;
    lsbuf[b] = fmaxf(ls, 1e-6f);
  }

  int dg = 0;
#pragma unroll
  for (int w = 0; w < 8; ++w) dg += __popc(adjw[t][w]);

  int lane = t & 63, wv = t >> 6;
  int x = dg;
#pragma unroll
  for (int off = 1; off < 64; off <<= 1) {
    int y = __shfl_up(x, off);
    if (lane >= off) x += y;
  }
  if (lane == 63) wsum[wv] = x;
  __syncthreads();
  if (t == 0) sbase = atomicAdd(gctr, wsum[0] + wsum[1] + wsum[2] + wsum[3]);
  __syncthreads();
  int woff = 0;
#pragma unroll
  for (int k2i = 0; k2i < 4; ++k2i) woff += (k2i < wv) ? wsum[k2i] : 0;
  int off0 = sbase + woff + x - dg;

  rowptr[r] = off0;
  deg[r] = dg;
  int o = off0;
#pragma unroll
  for (int w = 0; w < 8; ++w) {
    unsigned bits = adjw[t][w];
    while (bits) {
      int bp = __ffs(bits) - 1;
      colsb[o] = w * 32 + bp;
      rowof[o] = r;
      ++o;
      bits &= bits - 1;
    }
  }
}

// ---------- bf16 MFMA GEMM body: 16x64 tile, BK=64, reg prefetch + LDS dbuf
// AMODE: 0=bf16 A | 1=gated fp32 (gate +512, lda=1024) | 2=plain fp32 | 3=LN-fused fp32
// OMODE: 0=fp32 | 1=probe bf16/fp32 | 2=bf16
// K must be a multiple of 256. AMODE 3 requires K==256.
template <int AMODE, int OMODE>
__device__ __forceinline__ void mfma_body(const void* Aptr, int lda,
                                          const unsigned short* __restrict__ B, int ldb, int n0B,
                                          const float* __restrict__ bias,
                                          const float* resid,
                                          void* C, int ldc, int n0C,
                                          int m0, int K, bool obf,
                                          const float* __restrict__ lnG,
                                          const float* __restrict__ lnB) {
  __shared__ short As[2][16][72];
  __shared__ short Bs[2][64][72];
  __shared__ float sG[256], sB2[256];
  int t = threadIdx.x, lane = t & 63, w = t >> 6;

  int am = t >> 3, ak = (t & 7) * 8;   // A staging (t < 128): 16 rows x 64 k
  int bk = t >> 2, bn = (t & 3) * 16;  // B staging (all): 64 k x 64 n

  f32x4 acc;
  acc[0] = 0.f; acc[1] = 0.f; acc[2] = 0.f; acc[3] = 0.f;

  for (int kc = 0; kc < K; kc += 256) {
    // ---- prefetch 4 rounds of A and B into registers (independent loads) ----
    bf16x8 aB[4];
    float4 aF[4][2];
    float4 gF[4][2];
    bf16x8 bR[4][2];
#pragma unroll
    for (int r = 0; r < 4; ++r) {
      int k0 = kc + r * 64;
      if (t < 128) {
        if (AMODE == 0) {
          aB[r] = *(const bf16x8*)((const unsigned short*)Aptr +
                                   (size_t)(m0 + am) * lda + k0 + ak);
        } else {
          const float* ap = (const float*)Aptr + (size_t)(m0 + am) * lda + k0 + ak;
          aF[r][0] = *(const float4*)ap;
          aF[r][1] = *(const float4*)(ap + 4);
          if (AMODE == 1) {
            gF[r][0] = *(const float4*)(ap + 512);
            gF[r][1] = *(const float4*)(ap + 516);
          }
        }
      }
      const unsigned short* bp = B + (size_t)(k0 + bk) * ldb + n0B + bn;
      bR[r][0] = *(const bf16x8*)bp;
      bR[r][1] = *(const bf16x8*)(bp + 8);
    }

    // ---- AMODE 3: LN gamma/beta to LDS; row stats from prefetched regs ----
    float mm = 0.f, rstd = 0.f;
    if (AMODE == 3) {
      sG[t] = lnG[t]; sB2[t] = lnB[t];
      if (t < 128) {
        float s = 0.f, ss = 0.f;
#pragma unroll
        for (int r = 0; r < 4; ++r)
#pragma unroll
          for (int h2 = 0; h2 < 2; ++h2) {
            float4 v4 = aF[r][h2];
            s += v4.x + v4.y + v4.z + v4.w;
            ss += v4.x * v4.x + v4.y * v4.y + v4.z * v4.z + v4.w * v4.w;
          }
        s += __shfl_xor(s, 1); s += __shfl_xor(s, 2); s += __shfl_xor(s, 4);
        ss += __shfl_xor(ss, 1); ss += __shfl_xor(ss, 2); ss += __shfl_xor(ss, 4);
        mm = s * (1.f / 256.f);
        float var = ss * (1.f / 256.f) - mm * mm;
        rstd = 1.f / sqrtf(var + 1e-5f);
      }
      __syncthreads();
    }

    // ---- 4 rounds: stage buf[r&1] from regs; ONE sync; MFMA ----
#pragma unroll
    for (int r = 0; r < 4; ++r) {
      int bi = r & 1;
      if (t < 128) {
        if (AMODE == 0) {
          *(bf16x8*)&As[bi][am][ak] = aB[r];
        } else if (AMODE == 1) {
          float4 a0 = aF[r][0], a1 = aF[r][1];
          float4 g0 = gF[r][0], g1 = gF[r][1];
          short tmp[8];
          tmp[0] = (short)f2bf(a0.x * gelu_f(g0.x));
          tmp[1] = (short)f2bf(a0.y * gelu_f(g0.y));
          tmp[2] = (short)f2bf(a0.z * gelu_f(g0.z));
          tmp[3] = (short)f2bf(a0.w * gelu_f(g0.w));
          tmp[4] = (short)f2bf(a1.x * gelu_f(g1.x));
          tmp[5] = (short)f2bf(a1.y * gelu_f(g1.y));
          tmp[6] = (short)f2bf(a1.z * gelu_f(g1.z));
          tmp[7] = (short)f2bf(a1.w * gelu_f(g1.w));
          *(bf16x8*)&As[bi][am][ak] = *(bf16x8*)tmp;
        } else if (AMODE == 2) {
          float4 a0 = aF[r][0], a1 = aF[r][1];
          short tmp[8];
          tmp[0] = (short)f2bf(a0.x); tmp[1] = (short)f2bf(a0.y);
          tmp[2] = (short)f2bf(a0.z); tmp[3] = (short)f2bf(a0.w);
          tmp[4] = (short)f2bf(a1.x); tmp[5] = (short)f2bf(a1.y);
          tmp[6] = (short)f2bf(a1.z); tmp[7] = (short)f2bf(a1.w);
          *(bf16x8*)&As[bi][am][ak] = *(bf16x8*)tmp;
        } else {
          float4 a0 = aF[r][0], a1 = aF[r][1];
          int kb = kc + r * 64 + ak;
          short tmp[8];
          tmp[0] = (short)f2bf((a0.x - mm) * rstd * sG[kb + 0] + sB2[kb + 0]);
          tmp[1] = (short)f2bf((a0.y - mm) * rstd * sG[kb + 1] + sB2[kb + 1]);
          tmp[2] = (short)f2bf((a0.z - mm) * rstd * sG[kb + 2] + sB2[kb + 2]);
          tmp[3] = (short)f2bf((a0.w - mm) * rstd * sG[kb + 3] + sB2[kb + 3]);
          tmp[4] = (short)f2bf((a1.x - mm) * rstd * sG[kb + 4] + sB2[kb + 4]);
          tmp[5] = (short)f2bf((a1.y - mm) * rstd * sG[kb + 5] + sB2[kb + 5]);
          tmp[6] = (short)f2bf((a1.z - mm) * rstd * sG[kb + 6] + sB2[kb + 6]);
          tmp[7] = (short)f2bf((a1.w - mm) * rstd * sG[kb + 7] + sB2[kb + 7]);
          *(bf16x8*)&As[bi][am][ak] = *(bf16x8*)tmp;
        }
      }
      {
        bf16x8 bv0 = bR[r][0], bv1 = bR[r][1];
#pragma unroll
        for (int i2 = 0; i2 < 8; ++i2) Bs[bi][bn + i2][bk] = bv0[i2];
#pragma unroll
        for (int i2 = 0; i2 < 8; ++i2) Bs[bi][bn + 8 + i2][bk] = bv1[i2];
      }
      __syncthreads();
      int q = lane >> 4;
      bf16x8 af0 = *(const bf16x8*)&As[bi][lane & 15][q * 8];
      bf16x8 af1 = *(const bf16x8*)&As[bi][lane & 15][32 + q * 8];
      bf16x8 bf0 = *(const bf16x8*)&Bs[bi][w * 16 + (lane & 15)][q * 8];
      bf16x8 bf1 = *(const bf16x8*)&Bs[bi][w * 16 + (lane & 15)][32 + q * 8];
      acc = __builtin_amdgcn_mfma_f32_16x16x32_bf16(af0, bf0, acc, 0, 0, 0);
      acc = __builtin_amdgcn_mfma_f32_16x16x32_bf16(af1, bf1, acc, 0, 0, 0);
      // no trailing sync: next round stages the other buffer; reuse of this
      // buffer (r+2) is ordered by the next round's collective barrier.
    }
  }

  int q = lane >> 4;
  int cn = w * 16 + (lane & 15);
  int col = n0C + cn;
  float bv = bias ? bias[n0B + cn] : 0.0f;
#pragma unroll
  for (int rr = 0; rr < 4; ++rr) {
    int row = m0 + q * 4 + rr;
    float v = acc[rr] + bv;
    if (resid) v += resid[(size_t)row * ldc + col];
    if (OMODE == 2 || (OMODE == 1 && obf)) {
      ((unsigned short*)C)[(size_t)row * ldc + col] = f2bf(v);
    } else {
      ((float*)C)[(size_t)row * ldc + col] = v;
    }
  }
}

template <int AMODE, int OMODE>
__global__ __launch_bounds__(256) void k_mfma(const void* A, int lda, int aYoffBytes,
                                              const unsigned short* B, int ldb,
                                              const float* bias, const float* resid,
                                              void* C, int ldc, int K,
                                              const unsigned* probe,
                                              const float* lnG, const float* lnB) {
  bool obf = (OMODE == 1) && probe && (*probe != 0x3F800000u);
  int n0 = blockIdx.y * 64;
  const void* Ap = (const char*)A + (size_t)aYoffBytes * blockIdx.y;
  mfma_body<AMODE, OMODE>(Ap, lda, B, ldb, n0, bias, resid, C, ldc, n0,
                          blockIdx.x * 16, K, obf, lnG, lnB);
}

// QKV with fused LN: Wq/Wk/Wv sections are 131072 elems apart in the bf16 blob.
__global__ __launch_bounds__(256) void k_mfma_qkv(const float* X,
                                                  const float* lnG, const float* lnB,
                                                  const unsigned short* WqL, float* qkv) {
  int sel = blockIdx.y >> 2;
  const unsigned short* B = WqL + sel * 131072;
  int n0B = (blockIdx.y & 3) * 64;
  int n0C = blockIdx.y * 64;
  mfma_body<3, 0>(X, 256, B, 256, n0B, nullptr, nullptr, qkv, 768, n0C,
                  blockIdx.x * 16, 256, false, lnG, lnB);
}

// ---------- simz: sim + exp + rowsum atomics (edge-parallel) ----------
// Blocks 0..3 additionally zero the hub rows' tb/vs slots (r = bx*256).
__global__ __launch_bounds__(256) void k_simz(const float* __restrict__ cf,
                                              const float* __restrict__ qkv,
                                              const int* __restrict__ rowof,
                                              const int* __restrict__ colsb,
                                              const int* __restrict__ gctr,
                                              const float* __restrict__ lsbuf,
                                              const float* __restrict__ ebW1,
                                              const float* __restrict__ ebB1,
                                              const float* __restrict__ ebW2,
                                              const float* __restrict__ ebB2,
                                              float* __restrict__ esim,
                                              float* __restrict__ rowsum,
                                              float* __restrict__ tb,
                                              float* __restrict__ vs) {
  int t = threadIdx.x;
  if (blockIdx.x < 4) {
    int hr = blockIdx.x * 256;
    size_t tz = (size_t)hr * 1024 + t;
    tb[tz] = 0.f; tb[tz + 256] = 0.f; tb[tz + 512] = 0.f; tb[tz + 768] = 0.f;
    vs[(size_t)hr * 256 + t] = 0.f;
  }
  int E = *gctr;
  int lane = t & 63, w = t >> 6;
  float W1r[4][10], B1r[4], W2r[4][4];
#pragma unroll
  for (int kk = 0; kk < 4; ++kk) {
    int c = kk * 64 + lane;
    B1r[kk] = ebB1[c];
#pragma unroll
    for (int f = 0; f < 10; ++f) W1r[kk][f] = ebW1[f * 256 + c];
    float4 w2 = *(const float4*)(ebW2 + c * 4);
    W2r[kk][0] = w2.x; W2r[kk][1] = w2.y; W2r[kk][2] = w2.z; W2r[kk][3] = w2.w;
  }
  float b20 = ebB2[0], b21 = ebB2[1], b22 = ebB2[2], b23 = ebB2[3];
  for (int g = blockIdx.x * 4 + w; g < E; g += 4096) {
    int r = rowof[g], j = colsb[g];
    int b = r >> 8, i = r & 255;
    float ls = lsbuf[b];
    const float2* cc = (const float2*)cf;
    float2 ci = cc[b * 256 + i], cj = cc[b * 256 + j];
    float ef[10];
    edge_feats(i, j, ci.x, ci.y, cj.x, cj.y, ls, ef);
    float red[8];
#pragma unroll
    for (int z = 0; z < 8; ++z) red[z] = 0.0f;
#pragma unroll
    for (int kk = 0; kk < 4; ++kk) {
      int c = kk * 64 + lane;
      float h1 = B1r[kk];
#pragma unroll
      for (int f = 0; f < 10; ++f) h1 += ef[f] * W1r[kk][f];
      float g1 = gelu_f(h1);
      red[4] += g1 * W2r[kk][0];
      red[5] += g1 * W2r[kk][1];
      red[6] += g1 * W2r[kk][2];
      red[7] += g1 * W2r[kk][3];
      red[kk] = qkv[(size_t)r * 768 + c] * qkv[((size_t)(b * 256 + j)) * 768 + 256 + c];
    }
#pragma unroll
    for (int z = 0; z < 8; ++z) {
#pragma unroll
      for (int o = 32; o > 0; o >>= 1) red[z] += __shfl_xor(red[z], o);
    }
    if (lane == 0) {
      float e0 = expf(red[0] * 0.125f + red[4] + b20);
      float e1 = expf(red[1] * 0.125f + red[5] + b21);
      float e2 = expf(red[2] * 0.125f + red[6] + b22);
      float e3 = expf(red[3] * 0.125f + red[7] + b23);
      *(float4*)&esim[(size_t)g * 4] = make_float4(e0, e1, e2, e3);
      atomicAdd(&rowsum[r * 4 + 0], e0);
      atomicAdd(&rowsum[r * 4 + 1], e1);
      atomicAdd(&rowsum[r * 4 + 2], e2);
      atomicAdd(&rowsum[r * 4 + 3], e3);
    }
  }
}

// ---------- accum: hybrid chunked (32-edge chunks) ----------
// grid = 1052: x<1024 -> (row x, chunk 0); x>=1024 -> hub rows' chunks 1..7.
// Whole-row chunks (d<=32) store directly; hub chunks atomicAdd (slots
// pre-zeroed by k_simz).
__global__ __launch_bounds__(256, 8) void k_accum(const float* __restrict__ cf,
                                                  const float* __restrict__ qkv,
                                                  const int* __restrict__ rowptr,
                                                  const int* __restrict__ deg,
                                                  const int* __restrict__ colsb,
                                                  const float* __restrict__ esim,
                                                  const float* __restrict__ rowsum,
                                                  const float* __restrict__ lsbuf,
                                                  const float* __restrict__ evW1,
                                                  const float* __restrict__ evB1,
                                                  float* __restrict__ tb,
                                                  float* __restrict__ vs) {
  int x = blockIdx.x;
  int r, ch;
  if (x < 1024) { r = x; ch = 0; }
  else { int i5 = x - 1024; r = (i5 / 7) * 256; ch = 1 + i5 % 7; }
  int d = deg[r];
  int e0 = ch * 32;
  if (e0 >= d) return;
  int n = min(32, d - e0);
  bool whole = (ch == 0) && (d <= 32);
  int base = rowptr[r] + e0;
  int b = r >> 8, i = r & 255;
  int u = threadIdx.x, h = u >> 6;

  __shared__ int scols[32];
  __shared__ float4 sattn[32];
  __shared__ float sef[32][10];
  if (u < n) {
    float4 S4 = *(const float4*)&rowsum[r * 4];
    int j = colsb[base + u];
    scols[u] = j;
    float4 e = *(const float4*)&esim[(size_t)(base + u) * 4];
    sattn[u] = make_float4(e.x / S4.x, e.y / S4.y, e.z / S4.z, e.w / S4.w);
    float ls = lsbuf[b];
    const float2* cc = (const float2*)cf;
    float2 ci = cc[b * 256 + i], cj = cc[b * 256 + j];
    float ef[10];
    edge_feats(i, j, ci.x, ci.y, cj.x, cj.y, ls, ef);
#pragma unroll
    for (int f = 0; f < 10; ++f) sef[u][f] = ef[f];
  }
  __syncthreads();

  float evb = evB1[u];
  float w1r[10];
#pragma unroll
  for (int f = 0; f < 10; ++f) w1r[f] = evW1[f * 256 + u];
  float t0 = 0.f, t1 = 0.f, t2 = 0.f, t3 = 0.f, va = 0.f;
#pragma unroll 4
  for (int e = 0; e < n; ++e) {
    float4 a = sattn[e];
    int j = scols[e];
    float h1 = evb;
#pragma unroll
    for (int f = 0; f < 10; ++f) h1 += sef[e][f] * w1r[f];
    float g1 = gelu_f(h1);
    t0 += a.x * g1; t1 += a.y * g1; t2 += a.z * g1; t3 += a.w * g1;
    float ah = (h == 0) ? a.x : (h == 1) ? a.y : (h == 2) ? a.z : a.w;
    va += ah * qkv[((size_t)(b * 256 + j)) * 768 + 512 + u];
  }
  size_t tbase = (size_t)r * 1024 + u;
  if (whole) {
    tb[tbase]       = t0;
    tb[tbase + 256] = t1;
    tb[tbase + 512] = t2;
    tb[tbase + 768] = t3;
    vs[(size_t)r * 256 + u] = va;
  } else {
    atomicAdd(&tb[tbase], t0);
    atomicAdd(&tb[tbase + 256], t1);
    atomicAdd(&tb[tbase + 512], t2);
    atomicAdd(&tb[tbase + 768], t3);
    atomicAdd(&vs[(size_t)r * 256 + u], va);
  }
}

extern "C" void kernel_launch(void* const* d_in, const int* in_sizes, int n_in,
                              void* d_out, int out_size, void* d_ws, size_t ws_size,
                              hipStream_t stream) {
  (void)in_sizes; (void)n_in; (void)out_size; (void)ws_size;

  char* wp = (char*)d_ws;
  auto carve = [&](size_t bytes) -> char* {
    char* p = wp;
    wp += ((bytes + 255) / 256) * 256;
    return p;
  };
  int*   gctr   = (int*)carve(4);
  float* lsb    = (float*)carve(16);
  int*   valid  = (int*)carve(1024 * 4);
  int*   deg    = (int*)carve(1024 * 4);
  int*   rowptr = (int*)carve(1024 * 4);
  int*   rowof  = (int*)carve(MAXE * 4);
  int*   colsb  = (int*)carve(MAXE * 4);
  int*   knn    = (int*)carve(1024 * 3 * 4);
  float* rowsum = (float*)carve(8192 * 4);
  float* sim    = (float*)carve((size_t)MAXE * 16);
  float* blobF  = (float*)carve((size_t)(262144 + NONX) * 4);
  unsigned short* blobB = (unsigned short*)carve((size_t)BF16_TOTAL * 2);
  float* qkv    = (float*)carve((size_t)1024 * 768 * 4);
  float* xcur   = (float*)carve((size_t)262144 * 4);
  float* tb     = (float*)carve((size_t)1048576 * 4);   // t-accum; reused as FF hidden
  float* vs     = (float*)carve((size_t)262144 * 4);
  unsigned short* oi = (unsigned short*)carve((size_t)262144 * 2);

  // fp32 blob pointers
  const float* Xf    = blobF + 0;
  const float* Cf    = blobF + 262144;
  const float* ebW1  = blobF + 264192;
  const float* ebB1  = blobF + 269824;
  const float* ebW2  = blobF + 270336;
  const float* ebB2  = blobF + 272384;
  const float* evW1  = blobF + 272448;
  const float* evB1  = blobF + 278080;
  const float* evB2  = blobF + 278592;
  const float* boB   = blobF + 279104;
  const float* ln1w  = blobF + 279616;
  const float* ln1b  = blobF + 280128;
  const float* ln2w  = blobF + 280640;
  const float* ln2b  = blobF + 281152;
  const float* ffb1  = blobF + 281664;
  const float* ffb2  = blobF + 283712;
  // bf16 blob pointers
  const unsigned short* WqB   = blobB + 0;
  const unsigned short* WoB   = blobB + 393216;
  const unsigned short* evW2B = blobB + 524288;
  const unsigned short* ffw1B = blobB + 655360;
  const unsigned short* ffw2B = blobB + 1179648;

  PtrPack pp;
  for (int i = 0; i < 23; ++i) pp.p[i] = d_in[i];
  const unsigned* probe = (const unsigned*)d_in[15];

  k_convert<<<2048, 256, 0, stream>>>(pp, blobF, blobB, valid, rowsum, gctr);
  k_knn<<<256, 256, 0, stream>>>(Cf, valid, knn);
  k_csr<<<4, 256, 0, stream>>>(Cf, valid, knn, lsb, deg, rowptr, rowof, colsb, gctr);

  for (int l = 0; l < 2; ++l) {
    const float* xsrc = (l == 0) ? Xf : xcur;
    float* rsumL = rowsum + l * 4096;
    k_mfma_qkv<<<dim3(64, 12), 256, 0, stream>>>(xsrc, ln1w + l * 256, ln1b + l * 256,
                                                 WqB + l * 65536, qkv);
    k_simz<<<1024, 256, 0, stream>>>(Cf, qkv, rowof, colsb, gctr, lsb,
                                     ebW1 + l * 2816, ebB1 + l * 256,
                                     ebW2 + l * 1024, ebB2 + l * 4,
                                     sim, rsumL, tb, vs);
    k_accum<<<1052, 256, 0, stream>>>(Cf, qkv, rowptr, deg, colsb, sim, rsumL, lsb,
                                      evW1 + l * 2816, evB1 + l * 256, tb, vs);
    // epi GEMM: oi = vs + t_head @ evW2 + evB2   (A offset 256 floats per y-block)
    k_mfma<2, 2><<<dim3(64, 4), 256, 0, stream>>>(tb, 1024, 1024, evW2B + l * 65536, 256,
                                                  evB2 + l * 256, vs, oi, 256, 256,
                                                  nullptr, nullptr, nullptr);
    // Wo GEMM + residual
    k_mfma<0, 0><<<dim3(64, 4), 256, 0, stream>>>(oi, 256, 0, WoB + l * 65536, 256,
                                                  boB + l * 256, xsrc, xcur, 256, 256,
                                                  nullptr, nullptr, nullptr);
    // FF1 with fused LN2
    k_mfma<3, 0><<<dim3(64, 16), 256, 0, stream>>>(xcur, 256, 0, ffw1B + l * 262144, 1024,
                                                   ffb1 + l * 1024, nullptr, tb, 1024, 256,
                                                   nullptr, ln2w + l * 256, ln2b + l * 256);
    // FF2 gated + residual
    if (l == 0) {
      k_mfma<1, 0><<<dim3(64, 4), 256, 0, stream>>>(tb, 1024, 0, ffw2B + l * 131072, 256,
                                                    ffb2 + l * 256, xcur, xcur, 256, 512,
                                                    nullptr, nullptr, nullptr);
    } else {
      k_mfma<1, 1><<<dim3(64, 4), 256, 0, stream>>>(tb, 1024, 0, ffw2B + l * 131072, 256,
                                                    ffb2 + l * 256, xcur, d_out, 256, 512,
                                                    probe, nullptr, nullptr);
    }
  }
}